// Round 11
// baseline (294.824 us; speedup 1.0000x reference)
//
#include <hip/hip_runtime.h>
#include <math.h>

#define NEG_SLOPE 0.2f
#define LOG2E 1.4426950408889634f

typedef __attribute__((ext_vector_type(8))) short short8;   // 8 bf16 (4 VGPRs)
typedef __attribute__((ext_vector_type(4))) float f32x4;
typedef __attribute__((ext_vector_type(2))) float v2f;

typedef __attribute__((address_space(1))) unsigned int gu32;
typedef __attribute__((address_space(3))) unsigned int lu32;

__device__ __forceinline__ int imin(int a, int b) { return a < b ? a : b; }

__device__ __forceinline__ unsigned int f2bf(float f) {
    unsigned int u = __float_as_uint(f);
    return (u + 0x7fffu + ((u >> 16) & 1u)) >> 16;   // RNE
}
__device__ __forceinline__ float fast_exp2(float x) {
#if __has_builtin(__builtin_amdgcn_exp2f)
    return __builtin_amdgcn_exp2f(x);
#else
    return exp2f(x);
#endif
}
// fp8 (OCP e4m3 on gfx950) hardware pack/unpack
__device__ __forceinline__ unsigned char f2fp8(float v) {
    return (unsigned char)(__builtin_amdgcn_cvt_pk_fp8_f32(v, v, 0, false) & 0xff);
}
template <int CTRL>
__device__ __forceinline__ float dpp_add(float v) {
    int t = __builtin_amdgcn_update_dpp(0, __float_as_int(v), CTRL, 0xF, 0xF, true);
    return v + __int_as_float(t);
}
// gfx90a+ packed-FP32 VALU (2 channels / instruction) — hipcc scalarizes
// float2 arithmetic, so force the pk forms via asm.
__device__ __forceinline__ v2f pk_fma(v2f a, v2f b, v2f c) {
    v2f d;
    asm("v_pk_fma_f32 %0, %1, %2, %3" : "=v"(d) : "v"(a), "v"(b), "v"(c));
    return d;
}
__device__ __forceinline__ v2f pk_add(v2f a, v2f b) {
    v2f d;
    asm("v_pk_add_f32 %0, %1, %2" : "=v"(d) : "v"(a), "v"(b));
    return d;
}

// ---------------------------------------------------------------------------
// Fused prep kernel: three disjoint index ranges in one launch.
// ---------------------------------------------------------------------------
__global__ void fused_prep(const int* __restrict__ ei, const float* __restrict__ ea,
                           unsigned long long* __restrict__ hist, int E,
                           const float* __restrict__ x, unsigned short* __restrict__ xb, int nF4,
                           const float* __restrict__ W1l, const float* __restrict__ W1r,
                           const float* __restrict__ W2l, const float* __restrict__ W2r,
                           const float* __restrict__ b1l, const float* __restrict__ b1r,
                           const float* __restrict__ b2l, const float* __restrict__ b2r,
                           unsigned short* __restrict__ Wt1, unsigned short* __restrict__ Wt2,
                           float* __restrict__ b1cat, float* __restrict__ b2cat,
                           int F, int HC1, int HC2) {
    int i = blockIdx.x * blockDim.x + threadIdx.x;
    if (i < E) {
        int d = ei[E + i];
        long long fx = (long long)__float2int_rn(ea[i] * 65536.0f);
        unsigned long long v = ((unsigned long long)fx << 32) | 1ull;
        atomicAdd(&hist[(size_t)d * 8], v);
        return;
    }
    int j = i - E;
    if (j < nF4) {
        float4 v = ((const float4*)x)[j];
        uint2 r;
        r.x = f2bf(v.x) | (f2bf(v.y) << 16);
        r.y = f2bf(v.z) | (f2bf(v.w) << 16);
        ((uint2*)xb)[j] = r;
        return;
    }
    int k = j - nF4;
    int S1 = F * HC1, S2 = HC1 * HC2;
    if (k < S1) {
        int kk = k / HC1, nn = k - kk * HC1;
        Wt1[(size_t)nn * F + kk] = (unsigned short)f2bf(W1l[k]);
    } else if (k < 2 * S1) {
        int m = k - S1;
        int kk = m / HC1, nn = m - kk * HC1;
        Wt1[(size_t)(HC1 + nn) * F + kk] = (unsigned short)f2bf(W1r[m]);
    } else if (k < 2 * S1 + S2) {
        int m = k - 2 * S1;
        int kk = m / HC2, nn = m - kk * HC2;
        Wt2[(size_t)nn * HC1 + kk] = (unsigned short)f2bf(W2l[m]);
    } else if (k < 2 * S1 + 2 * S2) {
        int m = k - 2 * S1 - S2;
        int kk = m / HC2, nn = m - kk * HC2;
        Wt2[(size_t)(HC2 + nn) * HC1 + kk] = (unsigned short)f2bf(W2r[m]);
    } else if (k < 2 * S1 + 2 * S2 + 2 * HC1) {
        int m = k - 2 * S1 - 2 * S2;
        b1cat[m] = (m < HC1) ? b1l[m] : b1r[m - HC1];
    } else if (k < 2 * S1 + 2 * S2 + 2 * HC1 + 2 * HC2) {
        int m = k - 2 * S1 - 2 * S2 - 2 * HC1;
        b2cat[m] = (m < HC2) ? b2l[m] : b2r[m - HC2];
    }
}

// ---------------------------------------------------------------------------
// 2-phase parallel scan over hist (padded stride 8).
// ---------------------------------------------------------------------------
__global__ void scan_a(const unsigned long long* __restrict__ hist, int* __restrict__ bsum, int n) {
    __shared__ int wred[4];
    int base = blockIdx.x * 1024;
    int tid = threadIdx.x;
    int s = 0;
#pragma unroll
    for (int k = 0; k < 4; ++k) {
        int i = base + tid + k * 256;
        if (i < n) s += (int)(hist[(size_t)i * 8] & 0xffffffffull);
    }
#pragma unroll
    for (int off = 32; off > 0; off >>= 1) s += __shfl_xor(s, off, 64);
    if ((tid & 63) == 0) wred[tid >> 6] = s;
    __syncthreads();
    if (tid == 0) bsum[blockIdx.x] = wred[0] + wred[1] + wred[2] + wred[3];
}

__global__ void scan_c(const unsigned long long* __restrict__ hist,
                       const int* __restrict__ bsum, int* __restrict__ row_ptr,
                       int* __restrict__ wptr_pad, float* __restrict__ ea_loop,
                       int n, int B) {
    __shared__ int wtot[4];
    __shared__ int sh_base;
    int tid = threadIdx.x;
    int wid = tid >> 6, lane = tid & 63;
    int i0 = blockIdx.x * 1024 + tid * 4;
    int dcnt[4]; float esum[4];
#pragma unroll
    for (int k = 0; k < 4; ++k) {
        if (i0 + k < n) {
            unsigned long long h = hist[(size_t)(i0 + k) * 8];
            dcnt[k] = (int)(h & 0xffffffffull);
            esum[k] = (float)((int)(h >> 32)) * (1.0f / 65536.0f);
        } else { dcnt[k] = 0; esum[k] = 0.0f; }
    }
    int tsum = dcnt[0] + dcnt[1] + dcnt[2] + dcnt[3];
    int s = tsum;
#pragma unroll
    for (int off = 1; off < 64; off <<= 1) {
        int t = __shfl_up(s, off, 64);
        if (lane >= off) s += t;
    }
    if (lane == 63) wtot[wid] = s;
    if (tid < 64) {
        int v   = (tid < B) ? bsum[tid] : 0;
        int pre = (tid < (int)blockIdx.x) ? v : 0;
        int tot = v;
#pragma unroll
        for (int off = 32; off > 0; off >>= 1) {
            pre += __shfl_xor(pre, off, 64);
            tot += __shfl_xor(tot, off, 64);
        }
        if (tid == 0) {
            sh_base = pre;
            if (blockIdx.x == 0) row_ptr[n] = tot;
        }
    }
    __syncthreads();
    int wpre = 0;
#pragma unroll
    for (int k = 0; k < 4; ++k) if (k < wid) wpre += wtot[k];
    int pre = sh_base + wpre + (s - tsum);
    if (i0 < n) {
        int4 e;
        e.x = pre;
        e.y = pre + dcnt[0];
        e.z = e.y + dcnt[1];
        e.w = e.z + dcnt[2];
        *(int4*)(row_ptr + i0) = e;
        int ev[4] = { e.x, e.y, e.z, e.w };
        float4 el;
        el.x = esum[0] / fmaxf((float)dcnt[0], 1.0f);
        el.y = esum[1] / fmaxf((float)dcnt[1], 1.0f);
        el.z = esum[2] / fmaxf((float)dcnt[2], 1.0f);
        el.w = esum[3] / fmaxf((float)dcnt[3], 1.0f);
        *(float4*)(ea_loop + i0) = el;
#pragma unroll
        for (int k = 0; k < 4; ++k) wptr_pad[(size_t)(i0 + k) * 16] = ev[k];
    }
}

// ---------------------------------------------------------------------------
// scatter edges into CSR order; (src,w) packed as int2.
// ---------------------------------------------------------------------------
__global__ void edge_scatter(const int* __restrict__ ei, const float* __restrict__ ea,
                             int* __restrict__ wptr_pad, int2* __restrict__ spk, int E) {
    int e = blockIdx.x * blockDim.x + threadIdx.x;
    if (e < E) {
        int d = ei[E + e];
        int pos = atomicAdd(&wptr_pad[(size_t)d * 16], 1);
        spk[pos] = make_int2(ei[e], __float_as_int(ea[e]));
    }
}

// ---------------------------------------------------------------------------
// bf16 MFMA GEMM + bias (B pre-transposed), 64x64 tile, BK=32.
// OUT_FP8: epilogue packs to fp8 and splits cols into xl / xr dense tables.
// ---------------------------------------------------------------------------
template <bool OUT_FP8>
__global__ void __launch_bounds__(256)
gemm_bf16(const unsigned short* __restrict__ A, const unsigned short* __restrict__ Bt,
          const float* __restrict__ bias, void* __restrict__ Cv, void* __restrict__ Cv2,
          int split, int M, int N, int K) {
    __shared__ __attribute__((aligned(16))) unsigned short As[64 * 40];
    __shared__ __attribute__((aligned(16))) unsigned short Bs[64 * 40];
    int tid  = threadIdx.x;
    int wave = tid >> 6, lane = tid & 63;
    int m0 = blockIdx.x * 64, n0 = blockIdx.y * 64;
    int row = tid >> 2, kg = (tid & 3) * 8;

    f32x4 acc[4] = {};
    for (int kk = 0; kk < K; kk += 32) {
        int gm = m0 + row;
        uint4 av;
        if (gm < M) av = *(const uint4*)(A + (size_t)gm * K + kk + kg);
        else        av = make_uint4(0, 0, 0, 0);
        *(uint4*)&As[row * 40 + kg] = av;
        uint4 bv = *(const uint4*)(Bt + (size_t)(n0 + row) * K + kk + kg);
        *(uint4*)&Bs[row * 40 + kg] = bv;
        __syncthreads();
        short8 a = *(const short8*)&As[(wave * 16 + (lane & 15)) * 40 + (lane >> 4) * 8];
#pragma unroll
        for (int g = 0; g < 4; ++g) {
            short8 b = *(const short8*)&Bs[(g * 16 + (lane & 15)) * 40 + (lane >> 4) * 8];
            acc[g] = __builtin_amdgcn_mfma_f32_16x16x32_bf16(a, b, acc[g], 0, 0, 0);
        }
        __syncthreads();
    }
#pragma unroll
    for (int g = 0; g < 4; ++g) {
        int col = n0 + g * 16 + (lane & 15);
        float bs = bias[col];
#pragma unroll
        for (int r = 0; r < 4; ++r) {
            int grow = m0 + wave * 16 + (lane >> 4) * 4 + r;
            if (grow < M) {
                float val = acc[g][r] + bs;
                if constexpr (OUT_FP8) {
                    unsigned char c = f2fp8(val);
                    if (col < split) ((unsigned char*)Cv)[(size_t)grow * split + col] = c;
                    else             ((unsigned char*)Cv2)[(size_t)grow * split + (col - split)] = c;
                } else {
                    ((unsigned short*)Cv)[(size_t)grow * N + col] = (unsigned short)f2bf(val);
                }
            }
        }
    }
}

// ---------------------------------------------------------------------------
// helpers for gat_agg
// ---------------------------------------------------------------------------
template <int NV>
__device__ __forceinline__ void unp1(unsigned int u, v2f* xf) {
    xf[0] = __builtin_amdgcn_cvt_pk_f32_fp8(u, false);
    if constexpr (NV == 4) xf[1] = __builtin_amdgcn_cvt_pk_f32_fp8(u, true);
}
template <int G>
__device__ __forceinline__ float grp_reduce(float vs) {
    vs = dpp_add<0xB1>(vs);                               // xor 1
    if constexpr (G >= 4)  vs = dpp_add<0x4E>(vs);        // xor 2
    if constexpr (G >= 8)  vs = dpp_add<0x141>(vs);       // xor 4 (row_half_mirror)
    if constexpr (G >= 16) vs = dpp_add<0x140>(vs);       // xor 8 (row_mirror)
    if constexpr (G >= 32) {                              // xor 16
        int t = __builtin_amdgcn_ds_swizzle(__float_as_int(vs), 0x401F);
        vs += __int_as_float(t);
    }
    if constexpr (G >= 64) vs += __shfl_xor(vs, 32, 64);  // xor 32
    return vs;
}

// ---------------------------------------------------------------------------
// fused GATv2 gather(fp8) + score + softmax + aggregate + relu.
// ONE EDGE PER FULL WAVE; R11 CHANGE: the gather engine is an ASYNC DMA RING.
// Each edge's 256B row is fetched with __builtin_amdgcn_global_load_lds
// (per-lane global addr, wave-uniform LDS dest) into a private 16-slot LDS
// ring; 8 DMAs stay in flight (counted `s_waitcnt vmcnt(7)`, never 0 —
// T4 pattern).  In-flight data costs ZERO VGPRs, so deep cover (~8 edges
// ~450cy) coexists with a small register footprint (~high occupancy) —
// the combination the R2-R10 register pipelines were structurally denied
// (depth traded against the VGPR-48 occupancy cliff; all landed 41-48us).
// vmcnt counting is exact: the ring DMAs are the only VMEM ops in the loop
// (metas = scalar loads -> lgkm; reduce = DPP/DS -> lgkm; clamp-always-issue
// keeps outstanding == 8 invariant; asm memory clobber orders the ds_read).
// Consume: lane reads its NV bytes of the slot (lds offset == row offset).
// For NV==2 the DMA still loads 4B/lane (size must be 4): slot holds 256B
// = this row + next row's first 128B (tables have >=128B slack; harmless).
// OUT_MODE 0: dense bf16 rows.  OUT_MODE 1: LDS block-reduce + 128 atomics.
// ---------------------------------------------------------------------------
template <int HC, int C, int OUT_MODE>
__global__ void __launch_bounds__(256)
gat_agg(const unsigned char* __restrict__ xl, const unsigned char* __restrict__ xr,
        const float* __restrict__ We, const float* __restrict__ att,
        const float* __restrict__ bias,
        const int* __restrict__ row_ptr, const int2* __restrict__ spk,
        const float* __restrict__ ea_loop,
        void* __restrict__ out, int n) {
    constexpr int NV = HC / 64;      // channels (bytes) per lane, full-wave row
    constexpr int NG = (NV + 1) / 2; // v2f groups per lane
    constexpr int G  = C / NV;       // lanes per head
    constexpr int SHIFT = (HC == 256) ? 8 : 7;   // dense xl row stride
    constexpr float K23 = 2.0f / 3.0f;
    __shared__ __attribute__((aligned(16))) unsigned char ring[4][16 * 256];
    __shared__ float red[4][128];    // OUT_MODE 1 block pooling reduction
    int wave = threadIdx.x >> 6;
    int lane = threadIdx.x & 63;
    int node = blockIdx.x * 4 + wave;
    bool active = node < n;
    if (OUT_MODE == 0 && !active) return;
    unsigned int lo = (unsigned int)lane * NV;   // consume byte offset in row

    float vout[NV];
#pragma unroll
    for (int j = 0; j < NV; ++j) vout[j] = 0.0f;

    if (active) {
        unsigned char* myring = ring[wave];
        const unsigned char* gl = xl + (unsigned int)lane * 4;   // DMA lane base (4B/lane)

        auto ldd = [&](const unsigned char* base, unsigned int off) -> unsigned int {
            if constexpr (NV == 4) return *(const unsigned int*)(base + off);
            else                   return (unsigned int)(*(const unsigned short*)(base + off));
        };
        auto W = [&](int2 s) -> float { return __int_as_float(s.y); };

        v2f xr2[NG], We2[NG], att62[NG], o2[NG];
        {
            v2f tmp[NG];
            unp1<NV>(ldd(xr, ((unsigned int)node << SHIFT) + lo), tmp);
#pragma unroll
            for (int g = 0; g < NG; ++g) xr2[g] = tmp[g];
        }
#pragma unroll
        for (int g = 0; g < NG; ++g) {
            We2[g]   = *(const v2f*)(We  + lo + 2 * g);
            v2f a    = *(const v2f*)(att + lo + 2 * g);
            att62[g] = a * (0.6f * LOG2E);
            o2[g]    = v2f{0.0f, 0.0f};
        }
        float l = 0.0f;

        int start = __builtin_amdgcn_readfirstlane(row_ptr[node]);
        int end   = __builtin_amdgcn_readfirstlane(row_ptr[node + 1]);
        float ea_l = ea_loop[node];

        auto process = [&](unsigned int du, float w) {
            v2f xf[NG];
            unp1<NV>(du, xf);
            v2f w2 = {w, w};
            v2f vs6 = {0.0f, 0.0f};
            float vs4 = 0.0f;
#pragma unroll
            for (int g = 0; g < NG; ++g) {
                v2f t  = pk_fma(w2, We2[g], xr2[g]);     // xr + w*We
                v2f mm = pk_add(xf[g], t);               // xl[src] + xr + w*We
                vs6 = pk_fma(att62[g], mm, vs6);
                vs4 = fmaf(fabsf(mm.x), att62[g].x, vs4);
                vs4 = fmaf(fabsf(mm.y), att62[g].y, vs4);
            }
            float vs = fmaf(K23, vs4, vs6.x + vs6.y);
            vs = grp_reduce<G>(vs);
            float pr = fast_exp2(vs);
            l += pr;
            v2f pr2 = {pr, pr};
#pragma unroll
            for (int g = 0; g < NG; ++g) o2[g] = pk_fma(xf[g], pr2, o2[g]);
        };

        // ---- self-loop edge (register gather, consumed before the ring) ----
        process(ldd(xl, ((unsigned int)node << SHIFT) + lo), ea_l);

        int cnt = end - start;
        const int2* q = spk + start;   // wave-uniform meta (scalar loads)

        if (cnt > 0) {
            auto issue = [&](int k2, int slot) {
                int s = q[k2].x;   // uniform scalar load
                const unsigned char* gp = gl + ((size_t)(unsigned)s << SHIFT);
                __builtin_amdgcn_global_load_lds((const gu32*)gp,
                                                 (lu32*)(myring + slot * 256), 4, 0, 0);
            };
            // prologue: 8 DMAs in flight (edges 0..7, clamped)
#pragma unroll
            for (int j = 0; j < 8; ++j) issue(imin(j, cnt - 1), j);
            // steady state: consume edge k from slot k&15, keep 8 in flight.
            for (int k = 0; k < cnt; ++k) {
                asm volatile("s_waitcnt vmcnt(7)" ::: "memory");   // edge k landed
                unsigned int du;
                if constexpr (NV == 4)
                    du = *(const unsigned int*)(myring + (k & 15) * 256 + lo);
                else
                    du = (unsigned int)*(const unsigned short*)(myring + (k & 15) * 256 + lo);
                issue(imin(k + 8, cnt - 1), (k + 8) & 15);   // refill (slot k-8 mod 16)
                int2 t = q[k];
                process(du, W(t));
            }
        }

        // ---- epilogue ----
        float inv = 1.0f / (l + 1e-16f);
#pragma unroll
        for (int g = 0; g < NG; ++g) {
            v2f b = *(const v2f*)(bias + lo + 2 * g);
            vout[2 * g]     = fmaxf(o2[g].x * inv + b.x, 0.0f);
            vout[2 * g + 1] = fmaxf(o2[g].y * inv + b.y, 0.0f);
        }
        if constexpr (OUT_MODE == 0) {
            unsigned short* op = (unsigned short*)out + (size_t)node * HC + lo;
            if constexpr (NV == 4) {
                uint4* dummy;
                uint2 t;
                t.x = f2bf(vout[0]) | (f2bf(vout[1]) << 16);
                t.y = f2bf(vout[2]) | (f2bf(vout[3]) << 16);
                *(uint2*)op = t;
                (void)dummy;
            } else {
                *(unsigned int*)op = f2bf(vout[0]) | (f2bf(vout[1]) << 16);
            }
        }
    }

    if constexpr (OUT_MODE == 1) {
        // block-level pooling reduction: 4 waves -> LDS -> one atomic pass
#pragma unroll
        for (int j = 0; j < NV; ++j) red[wave][lo + j] = vout[j];
        __syncthreads();
        if (wave == 0) {
            int c = lane;   // channels c and c+64
            float a = red[0][c] + red[1][c] + red[2][c] + red[3][c];
            float b = red[0][c + 64] + red[1][c + 64] + red[2][c + 64] + red[3][c + 64];
            float* pacc = (float*)out + (size_t)(blockIdx.x & 255) * 128;
            atomicAdd(&pacc[c], a);
            atomicAdd(&pacc[c + 64], b);
        }
    }
}

// ---------------------------------------------------------------------------
// finish pooling, softmax over 128, sigmoid(alpha). 1024 threads.
// ---------------------------------------------------------------------------
__global__ void __launch_bounds__(1024)
pool_final(const float* __restrict__ partial, int nb,
           const float* __restrict__ alpha_in,
           float* __restrict__ out, int n) {
    __shared__ float acc[8][128];
    __shared__ float red[4];
    int t = threadIdx.x & 127;        // column
    int g = threadIdx.x >> 7;         // group 0..7
    float s = 0.0f;
    for (int b = g; b < nb; b += 8) s += partial[b * 128 + t];
    acc[g][t] = s;
    __syncthreads();
    if (threadIdx.x < 128) {
        float tot = 0.0f;
#pragma unroll
        for (int k = 0; k < 8; ++k) tot += acc[k][t];
        float mean = tot / (float)n;
        float mx = mean;
#pragma unroll
        for (int off = 32; off > 0; off >>= 1) mx = fmaxf(mx, __shfl_xor(mx, off, 64));
        if ((t & 63) == 0) red[t >> 6] = mx;
        __syncthreads();
        mx = fmaxf(red[0], red[1]);
        float ex = __expf(mean - mx);
        float sm = ex;
#pragma unroll
        for (int off = 32; off > 0; off >>= 1) sm += __shfl_xor(sm, off, 64);
        if ((t & 63) == 0) red[2 + (t >> 6)] = sm;
        __syncthreads();
        sm = red[2] + red[3];
        out[t] = ex / sm;
        if (t == 0) out[128] = 1.0f / (1.0f + __expf(-alpha_in[0]));
    }
}

// ---------------------------------------------------------------------------
extern "C" void kernel_launch(void* const* d_in, const int* in_sizes, int n_in,
                              void* d_out, int out_size, void* d_ws, size_t ws_size,
                              hipStream_t stream) {
    const float* x    = (const float*)d_in[0];
    const int*   ei   = (const int*)d_in[1];
    const float* ea   = (const float*)d_in[2];
    const float* W1l  = (const float*)d_in[3];
    const float* b1l  = (const float*)d_in[4];
    const float* W1r  = (const float*)d_in[5];
    const float* b1r  = (const float*)d_in[6];
    const float* We1  = (const float*)d_in[7];
    const float* att1 = (const float*)d_in[8];
    const float* bias1= (const float*)d_in[9];
    const float* W2l  = (const float*)d_in[10];
    const float* b2l  = (const float*)d_in[11];
    const float* W2r  = (const float*)d_in[12];
    const float* b2r  = (const float*)d_in[13];
    const float* We2  = (const float*)d_in[14];
    const float* att2 = (const float*)d_in[15];
    const float* bias2= (const float*)d_in[16];
    const float* alpha= (const float*)d_in[17];
    float* out = (float*)d_out;

    const int F = 128, HC1 = 256, HC2 = 128;
    const int n = in_sizes[0] / F;       // 20000
    const int E = in_sizes[1] / 2;       // 640000
    const int B = (n + 1023) / 1024;     // scan blocks

    char* ws = (char*)d_ws;
    size_t off = 0;
    auto alloc = [&](size_t bytes) { size_t p = off; off += (bytes + 255) & ~(size_t)255; return p; };

    unsigned long long* hist = (unsigned long long*)(ws + alloc((size_t)n * 8 * 8));  // padded x8
    int*   row_ptr = (int*)  (ws + alloc((size_t)(n + 1) * 4));
    int*   wptr    = (int*)  (ws + alloc((size_t)n * 16 * 4));                        // padded x16
    float* ea_loop = (float*)(ws + alloc((size_t)n * 4));
    int*   bsum    = (int*)  (ws + alloc(64 * 4));
    int2*  spk     = (int2*) (ws + alloc((size_t)E * 8));
    unsigned short* xb   = (unsigned short*)(ws + alloc((size_t)n * F * 2));
    unsigned short* Wt1  = (unsigned short*)(ws + alloc((size_t)F * (2 * HC1) * 2));
    unsigned short* Wt2  = (unsigned short*)(ws + alloc((size_t)HC1 * (2 * HC2) * 2));
    float* b1cat   = (float*)(ws + alloc((size_t)2 * HC1 * 4));
    float* b2cat   = (float*)(ws + alloc((size_t)2 * HC2 * 4));
    unsigned char* xl1 = (unsigned char*)(ws + alloc((size_t)n * HC1 + 256));  // dense fp8 xl (+DMA slack)
    unsigned char* xr1 = (unsigned char*)(ws + alloc((size_t)n * HC1 + 256));  // dense fp8 xr
    unsigned short* h1  = (unsigned short*)(ws + alloc((size_t)n * HC1 * 2));  // bf16
    float* partial = (float*)(ws + alloc((size_t)256 * 128 * 4));
    unsigned char* xl2 = xl1;   // layer-2 tables alias layer-1 (dead by then; slack holds)
    unsigned char* xr2 = xr1;
    const int NB_SLOTS = 256;

    (void)hipMemsetAsync(hist, 0, (size_t)n * 8 * 8, stream);
    (void)hipMemsetAsync(partial, 0, (size_t)NB_SLOTS * 128 * 4, stream);

    int tb = 256;
    {
        int nF4  = n * F / 4;
        int WTOT = 2 * F * HC1 + 2 * HC1 * HC2 + 2 * HC1 + 2 * HC2;
        int total = E + nF4 + WTOT;
        fused_prep<<<(total + tb - 1) / tb, tb, 0, stream>>>(
            ei, ea, hist, E, x, xb, nF4,
            W1l, W1r, W2l, W2r, b1l, b1r, b2l, b2r,
            Wt1, Wt2, b1cat, b2cat, F, HC1, HC2);
    }
    scan_a<<<B, 256, 0, stream>>>(hist, bsum, n);
    scan_c<<<B, 256, 0, stream>>>(hist, bsum, row_ptr, wptr, ea_loop, n, B);
    edge_scatter<<<(E + tb - 1) / tb, tb, 0, stream>>>(ei, ea, wptr, spk, E);

    // layer 1: merged GEMM [n,128]@[128,512] -> dense xl1 | xr1 (fp8)
    {
        dim3 grid((n + 63) / 64, (2 * HC1) / 64);
        gemm_bf16<true><<<grid, 256, 0, stream>>>(xb, Wt1, b1cat, xl1, xr1, HC1, n, 2 * HC1, F);
    }
    gat_agg<256, 32, 0><<<(n + 3) / 4, 256, 0, stream>>>(
        xl1, xr1, We1, att1, bias1, row_ptr, spk, ea_loop, h1, n);

    // layer 2: merged GEMM [n,256]@[256,256] -> dense xl2 | xr2 (fp8)
    {
        dim3 grid((n + 63) / 64, (2 * HC2) / 64);
        gemm_bf16<true><<<grid, 256, 0, stream>>>(h1, Wt2, b2cat, xl2, xr2, HC2, n, 2 * HC2, HC1);
    }
    // layer-2 gat with fused pooling (LDS block-reduce + per-block atomics)
    gat_agg<128, 128, 1><<<(n + 3) / 4, 256, 0, stream>>>(
        xl2, xr2, We2, att2, bias2, row_ptr, spk, ea_loop, partial, n);

    pool_final<<<1, 1024, 0, stream>>>(partial, NB_SLOTS, alpha, out, n);
}

// Round 12
// 274.947 us; speedup vs baseline: 1.0723x; 1.0723x over previous
//
#include <hip/hip_runtime.h>
#include <math.h>

#define NEG_SLOPE 0.2f
#define LOG2E 1.4426950408889634f

typedef __attribute__((ext_vector_type(8))) short short8;   // 8 bf16 (4 VGPRs)
typedef __attribute__((ext_vector_type(4))) float f32x4;
typedef __attribute__((ext_vector_type(2))) float v2f;

__device__ __forceinline__ int imin(int a, int b) { return a < b ? a : b; }

__device__ __forceinline__ unsigned int f2bf(float f) {
    unsigned int u = __float_as_uint(f);
    return (u + 0x7fffu + ((u >> 16) & 1u)) >> 16;   // RNE
}
__device__ __forceinline__ float fast_exp2(float x) {
#if __has_builtin(__builtin_amdgcn_exp2f)
    return __builtin_amdgcn_exp2f(x);
#else
    return exp2f(x);
#endif
}
// fp8 (OCP e4m3 on gfx950) hardware pack/unpack
__device__ __forceinline__ unsigned char f2fp8(float v) {
    return (unsigned char)(__builtin_amdgcn_cvt_pk_fp8_f32(v, v, 0, false) & 0xff);
}
template <int CTRL>
__device__ __forceinline__ float dpp_add(float v) {
    int t = __builtin_amdgcn_update_dpp(0, __float_as_int(v), CTRL, 0xF, 0xF, true);
    return v + __int_as_float(t);
}
// gfx90a+ packed-FP32 VALU (2 channels / instruction) — hipcc scalarizes
// float2 arithmetic, so force the pk forms via asm.
__device__ __forceinline__ v2f pk_fma(v2f a, v2f b, v2f c) {
    v2f d;
    asm("v_pk_fma_f32 %0, %1, %2, %3" : "=v"(d) : "v"(a), "v"(b), "v"(c));
    return d;
}
__device__ __forceinline__ v2f pk_add(v2f a, v2f b) {
    v2f d;
    asm("v_pk_add_f32 %0, %1, %2" : "=v"(d) : "v"(a), "v"(b));
    return d;
}

// ---------------------------------------------------------------------------
// Fused prep kernel: three disjoint index ranges in one launch.
//  [0, E)            : packed histogram (64-bit atomic, 64B-padded slots)
//  [E, E+nF4)        : x fp32 -> bf16 (vec4)
//  [E+nF4, ..+WTOT)  : weight transposes -> bf16 + bias concats
// ---------------------------------------------------------------------------
__global__ void fused_prep(const int* __restrict__ ei, const float* __restrict__ ea,
                           unsigned long long* __restrict__ hist, int E,
                           const float* __restrict__ x, unsigned short* __restrict__ xb, int nF4,
                           const float* __restrict__ W1l, const float* __restrict__ W1r,
                           const float* __restrict__ W2l, const float* __restrict__ W2r,
                           const float* __restrict__ b1l, const float* __restrict__ b1r,
                           const float* __restrict__ b2l, const float* __restrict__ b2r,
                           unsigned short* __restrict__ Wt1, unsigned short* __restrict__ Wt2,
                           float* __restrict__ b1cat, float* __restrict__ b2cat,
                           int F, int HC1, int HC2) {
    int i = blockIdx.x * blockDim.x + threadIdx.x;
    if (i < E) {
        int d = ei[E + i];
        long long fx = (long long)__float2int_rn(ea[i] * 65536.0f);
        unsigned long long v = ((unsigned long long)fx << 32) | 1ull;
        atomicAdd(&hist[(size_t)d * 8], v);
        return;
    }
    int j = i - E;
    if (j < nF4) {
        float4 v = ((const float4*)x)[j];
        uint2 r;
        r.x = f2bf(v.x) | (f2bf(v.y) << 16);
        r.y = f2bf(v.z) | (f2bf(v.w) << 16);
        ((uint2*)xb)[j] = r;
        return;
    }
    int k = j - nF4;
    int S1 = F * HC1, S2 = HC1 * HC2;
    if (k < S1) {
        int kk = k / HC1, nn = k - kk * HC1;
        Wt1[(size_t)nn * F + kk] = (unsigned short)f2bf(W1l[k]);
    } else if (k < 2 * S1) {
        int m = k - S1;
        int kk = m / HC1, nn = m - kk * HC1;
        Wt1[(size_t)(HC1 + nn) * F + kk] = (unsigned short)f2bf(W1r[m]);
    } else if (k < 2 * S1 + S2) {
        int m = k - 2 * S1;
        int kk = m / HC2, nn = m - kk * HC2;
        Wt2[(size_t)nn * HC1 + kk] = (unsigned short)f2bf(W2l[m]);
    } else if (k < 2 * S1 + 2 * S2) {
        int m = k - 2 * S1 - S2;
        int kk = m / HC2, nn = m - kk * HC2;
        Wt2[(size_t)(HC2 + nn) * HC1 + kk] = (unsigned short)f2bf(W2r[m]);
    } else if (k < 2 * S1 + 2 * S2 + 2 * HC1) {
        int m = k - 2 * S1 - 2 * S2;
        b1cat[m] = (m < HC1) ? b1l[m] : b1r[m - HC1];
    } else if (k < 2 * S1 + 2 * S2 + 2 * HC1 + 2 * HC2) {
        int m = k - 2 * S1 - 2 * S2 - 2 * HC1;
        b2cat[m] = (m < HC2) ? b2l[m] : b2r[m - HC2];
    }
}

// ---------------------------------------------------------------------------
// 2-phase parallel scan over hist (padded stride 8): scan_a computes raw
// block sums; scan_c derives its own prefix from bsum in-wave (scan_b folded).
// ---------------------------------------------------------------------------
__global__ void scan_a(const unsigned long long* __restrict__ hist, int* __restrict__ bsum, int n) {
    __shared__ int wred[4];
    int base = blockIdx.x * 1024;
    int tid = threadIdx.x;
    int s = 0;
#pragma unroll
    for (int k = 0; k < 4; ++k) {
        int i = base + tid + k * 256;
        if (i < n) s += (int)(hist[(size_t)i * 8] & 0xffffffffull);
    }
#pragma unroll
    for (int off = 32; off > 0; off >>= 1) s += __shfl_xor(s, off, 64);
    if ((tid & 63) == 0) wred[tid >> 6] = s;
    __syncthreads();
    if (tid == 0) bsum[blockIdx.x] = wred[0] + wred[1] + wred[2] + wred[3];
}

__global__ void scan_c(const unsigned long long* __restrict__ hist,
                       const int* __restrict__ bsum, int* __restrict__ row_ptr,
                       int* __restrict__ wptr_pad, float* __restrict__ ea_loop,
                       int n, int B) {
    __shared__ int wtot[4];
    __shared__ int sh_base;
    int tid = threadIdx.x;
    int wid = tid >> 6, lane = tid & 63;
    int i0 = blockIdx.x * 1024 + tid * 4;
    int dcnt[4]; float esum[4];
#pragma unroll
    for (int k = 0; k < 4; ++k) {
        if (i0 + k < n) {
            unsigned long long h = hist[(size_t)(i0 + k) * 8];
            dcnt[k] = (int)(h & 0xffffffffull);
            esum[k] = (float)((int)(h >> 32)) * (1.0f / 65536.0f);
        } else { dcnt[k] = 0; esum[k] = 0.0f; }
    }
    int tsum = dcnt[0] + dcnt[1] + dcnt[2] + dcnt[3];
    int s = tsum;
#pragma unroll
    for (int off = 1; off < 64; off <<= 1) {
        int t = __shfl_up(s, off, 64);
        if (lane >= off) s += t;
    }
    if (lane == 63) wtot[wid] = s;
    // wave 0: block prefix (sum of bsum[0..blockIdx)) and grand total
    if (tid < 64) {
        int v   = (tid < B) ? bsum[tid] : 0;
        int pre = (tid < (int)blockIdx.x) ? v : 0;
        int tot = v;
#pragma unroll
        for (int off = 32; off > 0; off >>= 1) {
            pre += __shfl_xor(pre, off, 64);
            tot += __shfl_xor(tot, off, 64);
        }
        if (tid == 0) {
            sh_base = pre;
            if (blockIdx.x == 0) row_ptr[n] = tot;
        }
    }
    __syncthreads();
    int wpre = 0;
#pragma unroll
    for (int k = 0; k < 4; ++k) if (k < wid) wpre += wtot[k];
    int pre = sh_base + wpre + (s - tsum);
    if (i0 < n) {
        int4 e;
        e.x = pre;
        e.y = pre + dcnt[0];
        e.z = e.y + dcnt[1];
        e.w = e.z + dcnt[2];
        *(int4*)(row_ptr + i0) = e;
        int ev[4] = { e.x, e.y, e.z, e.w };
        float4 el;
        el.x = esum[0] / fmaxf((float)dcnt[0], 1.0f);
        el.y = esum[1] / fmaxf((float)dcnt[1], 1.0f);
        el.z = esum[2] / fmaxf((float)dcnt[2], 1.0f);
        el.w = esum[3] / fmaxf((float)dcnt[3], 1.0f);
        *(float4*)(ea_loop + i0) = el;
#pragma unroll
        for (int k = 0; k < 4; ++k) wptr_pad[(size_t)(i0 + k) * 16] = ev[k];
    }
}

// ---------------------------------------------------------------------------
// scatter edges into CSR order; (src,w) packed as int2.
// ---------------------------------------------------------------------------
__global__ void edge_scatter(const int* __restrict__ ei, const float* __restrict__ ea,
                             int* __restrict__ wptr_pad, int2* __restrict__ spk, int E) {
    int e = blockIdx.x * blockDim.x + threadIdx.x;
    if (e < E) {
        int d = ei[E + e];
        int pos = atomicAdd(&wptr_pad[(size_t)d * 16], 1);
        spk[pos] = make_int2(ei[e], __float_as_int(ea[e]));
    }
}

// ---------------------------------------------------------------------------
// bf16 MFMA GEMM + bias (B pre-transposed), 64x64 tile, BK=32.
// OUT_FP8: epilogue packs to fp8 and SPLITS the output: cols [0,split) go to
// Cv (dense xl table), cols [split,N) to Cv2 (dense xr table) — each with
// row stride = split bytes.  Shrinks the gather working set to L2-fit.
// ---------------------------------------------------------------------------
template <bool OUT_FP8>
__global__ void __launch_bounds__(256)
gemm_bf16(const unsigned short* __restrict__ A, const unsigned short* __restrict__ Bt,
          const float* __restrict__ bias, void* __restrict__ Cv, void* __restrict__ Cv2,
          int split, int M, int N, int K) {
    __shared__ __attribute__((aligned(16))) unsigned short As[64 * 40];
    __shared__ __attribute__((aligned(16))) unsigned short Bs[64 * 40];
    int tid  = threadIdx.x;
    int wave = tid >> 6, lane = tid & 63;
    int m0 = blockIdx.x * 64, n0 = blockIdx.y * 64;
    int row = tid >> 2, kg = (tid & 3) * 8;

    f32x4 acc[4] = {};
    for (int kk = 0; kk < K; kk += 32) {
        int gm = m0 + row;
        uint4 av;
        if (gm < M) av = *(const uint4*)(A + (size_t)gm * K + kk + kg);
        else        av = make_uint4(0, 0, 0, 0);
        *(uint4*)&As[row * 40 + kg] = av;
        uint4 bv = *(const uint4*)(Bt + (size_t)(n0 + row) * K + kk + kg);
        *(uint4*)&Bs[row * 40 + kg] = bv;
        __syncthreads();
        short8 a = *(const short8*)&As[(wave * 16 + (lane & 15)) * 40 + (lane >> 4) * 8];
#pragma unroll
        for (int g = 0; g < 4; ++g) {
            short8 b = *(const short8*)&Bs[(g * 16 + (lane & 15)) * 40 + (lane >> 4) * 8];
            acc[g] = __builtin_amdgcn_mfma_f32_16x16x32_bf16(a, b, acc[g], 0, 0, 0);
        }
        __syncthreads();
    }
#pragma unroll
    for (int g = 0; g < 4; ++g) {
        int col = n0 + g * 16 + (lane & 15);
        float bs = bias[col];
#pragma unroll
        for (int r = 0; r < 4; ++r) {
            int grow = m0 + wave * 16 + (lane >> 4) * 4 + r;
            if (grow < M) {
                float val = acc[g][r] + bs;
                if constexpr (OUT_FP8) {
                    unsigned char c = f2fp8(val);
                    if (col < split) ((unsigned char*)Cv)[(size_t)grow * split + col] = c;
                    else             ((unsigned char*)Cv2)[(size_t)grow * split + (col - split)] = c;
                } else {
                    ((unsigned short*)Cv)[(size_t)grow * N + col] = (unsigned short)f2bf(val);
                }
            }
        }
    }
}

// ---------------------------------------------------------------------------
// helpers for gat_agg (fp8 gather, packed-f32 math)
// ---------------------------------------------------------------------------
template <int NV>
__device__ __forceinline__ void unp1(unsigned int u, v2f* xf) {
    xf[0] = __builtin_amdgcn_cvt_pk_f32_fp8(u, false);
    if constexpr (NV == 4) xf[1] = __builtin_amdgcn_cvt_pk_f32_fp8(u, true);
}
// reduction over G consecutive lanes (G-aligned groups), full 64-lane wave
template <int G>
__device__ __forceinline__ float grp_reduce(float vs) {
    vs = dpp_add<0xB1>(vs);                               // xor 1
    if constexpr (G >= 4)  vs = dpp_add<0x4E>(vs);        // xor 2
    if constexpr (G >= 8)  vs = dpp_add<0x141>(vs);       // xor 4 (row_half_mirror)
    if constexpr (G >= 16) vs = dpp_add<0x140>(vs);       // xor 8 (row_mirror)
    if constexpr (G >= 32) {                              // xor 16
        int t = __builtin_amdgcn_ds_swizzle(__float_as_int(vs), 0x401F);
        vs += __int_as_float(t);
    }
    if constexpr (G >= 64) vs += __shfl_xor(vs, 32, 64);  // xor 32
    return vs;
}

// ---------------------------------------------------------------------------
// fused GATv2 gather(fp8) + score + softmax + aggregate + relu.
// ONE EDGE PER FULL WAVE (64 lanes x NV=HC/64 channels), depth-6 mov-free
// register gather pipeline, dense xl/xr split tables (R10 config — best
// measured tier, 274.7us total, L1 gat ~42us).  R11's async-DMA ring
// regressed (per-edge vmcnt wait serialization + LDS round trip) and is
// reverted.  Ledger R2-R11: issue-count, ILP depth 2-10, TLP 29-61% occ,
// working-set 10->5MB, async DMA — all land 41-50us/layer; the phase sits
// at ~1.6x its own VALU-issue floor with latency and issue floors crossing
// at ~40us.  This is the structural plateau of the gather-softmax phase.
// OUT_MODE 0: dense bf16 rows.
// OUT_MODE 1: LDS block-reduction (4 waves) then 128 atomics per BLOCK.
// ---------------------------------------------------------------------------
template <int HC, int C, int OUT_MODE>
__global__ void __launch_bounds__(256)
gat_agg(const unsigned char* __restrict__ xl, const unsigned char* __restrict__ xr,
        const float* __restrict__ We, const float* __restrict__ att,
        const float* __restrict__ bias,
        const int* __restrict__ row_ptr, const int2* __restrict__ spk,
        const float* __restrict__ ea_loop,
        void* __restrict__ out, int n) {
    constexpr int NV = HC / 64;      // channels (bytes) per lane, full-wave row
    constexpr int NG = (NV + 1) / 2; // v2f groups per lane (NV=4 -> 2, NV=2 -> 1)
    constexpr int G  = C / NV;       // lanes per head
    constexpr int SHIFT = (HC == 256) ? 8 : 7;   // dense xl row stride
    constexpr float K23 = 2.0f / 3.0f;
    __shared__ float red[4][128];    // OUT_MODE 1 block pooling reduction
    int wave = threadIdx.x >> 6;
    int lane = threadIdx.x & 63;
    int node = blockIdx.x * 4 + wave;
    bool active = node < n;
    if (OUT_MODE == 0 && !active) return;
    unsigned int lo = (unsigned int)lane * NV;   // channel/byte offset

    float vout[NV];
#pragma unroll
    for (int j = 0; j < NV; ++j) vout[j] = 0.0f;

    if (active) {
        auto ldd = [&](const unsigned char* base, unsigned int off) -> unsigned int {
            if constexpr (NV == 4) return *(const unsigned int*)(base + off);
            else                   return (unsigned int)(*(const unsigned short*)(base + off));
        };
        auto gat = [&](int s) -> unsigned int {
            return ldd(xl, ((unsigned int)s << SHIFT) + lo);
        };
        auto W = [&](int2 s) -> float { return __int_as_float(s.y); };

        v2f xr2[NG], We2[NG], att62[NG], o2[NG];
        {
            v2f tmp[NG];
            unp1<NV>(ldd(xr, ((unsigned int)node << SHIFT) + lo), tmp);
#pragma unroll
            for (int g = 0; g < NG; ++g) xr2[g] = tmp[g];
        }
#pragma unroll
        for (int g = 0; g < NG; ++g) {
            We2[g]   = *(const v2f*)(We  + lo + 2 * g);
            v2f a    = *(const v2f*)(att + lo + 2 * g);
            att62[g] = a * (0.6f * LOG2E);
            o2[g]    = v2f{0.0f, 0.0f};
        }
        float l = 0.0f;

        int start = __builtin_amdgcn_readfirstlane(row_ptr[node]);
        int end   = __builtin_amdgcn_readfirstlane(row_ptr[node + 1]);
        float ea_l = ea_loop[node];

        auto process = [&](unsigned int du, float w) {
            v2f xf[NG];
            unp1<NV>(du, xf);
            v2f w2 = {w, w};
            v2f vs6 = {0.0f, 0.0f};
            float vs4 = 0.0f;
#pragma unroll
            for (int g = 0; g < NG; ++g) {
                v2f t  = pk_fma(w2, We2[g], xr2[g]);     // xr + w*We
                v2f mm = pk_add(xf[g], t);               // xl[src] + xr + w*We
                vs6 = pk_fma(att62[g], mm, vs6);
                vs4 = fmaf(fabsf(mm.x), att62[g].x, vs4);   // abs = free modifier
                vs4 = fmaf(fabsf(mm.y), att62[g].y, vs4);
            }
            float vs = fmaf(K23, vs4, vs6.x + vs6.y);
            vs = grp_reduce<G>(vs);
            float pr = fast_exp2(vs);
            l += pr;
            v2f pr2 = {pr, pr};
#pragma unroll
            for (int g = 0; g < NG; ++g) o2[g] = pk_fma(xf[g], pr2, o2[g]);
        };

        // ---- self-loop edge ----
        process(gat(node), ea_l);

        // ---- real edges: 6-deep mov-free gather pipeline ----
        int cnt = end - start;
        const int2* q = spk + start;   // wave-uniform meta per edge

        if (cnt >= 6) {
            int2 t;
            t = q[0]; unsigned int g0 = gat(t.x); float w0 = W(t);
            t = q[1]; unsigned int g1 = gat(t.x); float w1 = W(t);
            t = q[2]; unsigned int g2 = gat(t.x); float w2 = W(t);
            t = q[3]; unsigned int g3 = gat(t.x); float w3 = W(t);
            t = q[4]; unsigned int g4 = gat(t.x); float w4 = W(t);
            t = q[5]; unsigned int g5 = gat(t.x); float w5 = W(t);
            int p = 0;
            // invariant at loop top: g0..g5 / w0..w5 hold edges p..p+5
            for (; p + 12 <= cnt; p += 6) {
                process(g0, w0); t = q[p + 6];  g0 = gat(t.x); w0 = W(t);
                process(g1, w1); t = q[p + 7];  g1 = gat(t.x); w1 = W(t);
                process(g2, w2); t = q[p + 8];  g2 = gat(t.x); w2 = W(t);
                process(g3, w3); t = q[p + 9];  g3 = gat(t.x); w3 = W(t);
                process(g4, w4); t = q[p + 10]; g4 = gat(t.x); w4 = W(t);
                process(g5, w5); t = q[p + 11]; g5 = gat(t.x); w5 = W(t);
            }
            // r = cnt - p in [6, 11]
            process(g0, w0); process(g1, w1); process(g2, w2);
            process(g3, w3); process(g4, w4); process(g5, w5);
            for (int k = p + 6; k < cnt; ++k) {
                t = q[k];
                process(gat(t.x), W(t));
            }
        } else {
            for (int k = 0; k < cnt; ++k) {
                int2 t = q[k];
                process(gat(t.x), W(t));
            }
        }

        // ---- epilogue: every lane owns its NV channels and full head denom ----
        float inv = 1.0f / (l + 1e-16f);
#pragma unroll
        for (int g = 0; g < NG; ++g) {
            v2f b = *(const v2f*)(bias + lo + 2 * g);
            vout[2 * g]     = fmaxf(o2[g].x * inv + b.x, 0.0f);
            vout[2 * g + 1] = fmaxf(o2[g].y * inv + b.y, 0.0f);
        }
        if constexpr (OUT_MODE == 0) {
            unsigned short* op = (unsigned short*)out + (size_t)node * HC + lo;
            if constexpr (NV == 4) {
                uint2 t;
                t.x = f2bf(vout[0]) | (f2bf(vout[1]) << 16);
                t.y = f2bf(vout[2]) | (f2bf(vout[3]) << 16);
                *(uint2*)op = t;
            } else {
                *(unsigned int*)op = f2bf(vout[0]) | (f2bf(vout[1]) << 16);
            }
        }
    }

    if constexpr (OUT_MODE == 1) {
        // block-level pooling reduction: 4 waves -> LDS -> one atomic pass
#pragma unroll
        for (int j = 0; j < NV; ++j) red[wave][lo + j] = vout[j];
        __syncthreads();
        if (wave == 0) {
            int c = lane;   // channels c and c+64
            float a = red[0][c] + red[1][c] + red[2][c] + red[3][c];
            float b = red[0][c + 64] + red[1][c + 64] + red[2][c + 64] + red[3][c + 64];
            float* pacc = (float*)out + (size_t)(blockIdx.x & 255) * 128;
            atomicAdd(&pacc[c], a);
            atomicAdd(&pacc[c + 64], b);
        }
    }
}

// ---------------------------------------------------------------------------
// finish pooling, softmax over 128, sigmoid(alpha). 1024 threads.
// ---------------------------------------------------------------------------
__global__ void __launch_bounds__(1024)
pool_final(const float* __restrict__ partial, int nb,
           const float* __restrict__ alpha_in,
           float* __restrict__ out, int n) {
    __shared__ float acc[8][128];
    __shared__ float red[4];
    int t = threadIdx.x & 127;        // column
    int g = threadIdx.x >> 7;         // group 0..7
    float s = 0.0f;
    for (int b = g; b < nb; b += 8) s += partial[b * 128 + t];
    acc[g][t] = s;
    __syncthreads();
    if (threadIdx.x < 128) {
        float tot = 0.0f;
#pragma unroll
        for (int k = 0; k < 8; ++k) tot += acc[k][t];
        float mean = tot / (float)n;
        float mx = mean;
#pragma unroll
        for (int off = 32; off > 0; off >>= 1) mx = fmaxf(mx, __shfl_xor(mx, off, 64));
        if ((t & 63) == 0) red[t >> 6] = mx;
        __syncthreads();
        mx = fmaxf(red[0], red[1]);
        float ex = __expf(mean - mx);
        float sm = ex;
#pragma unroll
        for (int off = 32; off > 0; off >>= 1) sm += __shfl_xor(sm, off, 64);
        if ((t & 63) == 0) red[2 + (t >> 6)] = sm;
        __syncthreads();
        sm = red[2] + red[3];
        out[t] = ex / sm;
        if (t == 0) out[128] = 1.0f / (1.0f + __expf(-alpha_in[0]));
    }
}

// ---------------------------------------------------------------------------
extern "C" void kernel_launch(void* const* d_in, const int* in_sizes, int n_in,
                              void* d_out, int out_size, void* d_ws, size_t ws_size,
                              hipStream_t stream) {
    const float* x    = (const float*)d_in[0];
    const int*   ei   = (const int*)d_in[1];
    const float* ea   = (const float*)d_in[2];
    const float* W1l  = (const float*)d_in[3];
    const float* b1l  = (const float*)d_in[4];
    const float* W1r  = (const float*)d_in[5];
    const float* b1r  = (const float*)d_in[6];
    const float* We1  = (const float*)d_in[7];
    const float* att1 = (const float*)d_in[8];
    const float* bias1= (const float*)d_in[9];
    const float* W2l  = (const float*)d_in[10];
    const float* b2l  = (const float*)d_in[11];
    const float* W2r  = (const float*)d_in[12];
    const float* b2r  = (const float*)d_in[13];
    const float* We2  = (const float*)d_in[14];
    const float* att2 = (const float*)d_in[15];
    const float* bias2= (const float*)d_in[16];
    const float* alpha= (const float*)d_in[17];
    float* out = (float*)d_out;

    const int F = 128, HC1 = 256, HC2 = 128;
    const int n = in_sizes[0] / F;       // 20000
    const int E = in_sizes[1] / 2;       // 640000
    const int B = (n + 1023) / 1024;     // scan blocks

    char* ws = (char*)d_ws;
    size_t off = 0;
    auto alloc = [&](size_t bytes) { size_t p = off; off += (bytes + 255) & ~(size_t)255; return p; };

    unsigned long long* hist = (unsigned long long*)(ws + alloc((size_t)n * 8 * 8));  // padded x8
    int*   row_ptr = (int*)  (ws + alloc((size_t)(n + 1) * 4));
    int*   wptr    = (int*)  (ws + alloc((size_t)n * 16 * 4));                        // padded x16
    float* ea_loop = (float*)(ws + alloc((size_t)n * 4));
    int*   bsum    = (int*)  (ws + alloc(64 * 4));
    int2*  spk     = (int2*) (ws + alloc((size_t)E * 8));
    unsigned short* xb   = (unsigned short*)(ws + alloc((size_t)n * F * 2));
    unsigned short* Wt1  = (unsigned short*)(ws + alloc((size_t)F * (2 * HC1) * 2));
    unsigned short* Wt2  = (unsigned short*)(ws + alloc((size_t)HC1 * (2 * HC2) * 2));
    float* b1cat   = (float*)(ws + alloc((size_t)2 * HC1 * 4));
    float* b2cat   = (float*)(ws + alloc((size_t)2 * HC2 * 4));
    unsigned char* xl1 = (unsigned char*)(ws + alloc((size_t)n * HC1));   // dense fp8 xl table
    unsigned char* xr1 = (unsigned char*)(ws + alloc((size_t)n * HC1));   // dense fp8 xr table
    unsigned short* h1  = (unsigned short*)(ws + alloc((size_t)n * HC1 * 2));  // bf16
    float* partial = (float*)(ws + alloc((size_t)256 * 128 * 4));
    unsigned char* xl2 = xl1;   // layer-2 tables alias layer-1 (dead by then)
    unsigned char* xr2 = xr1;
    const int NB_SLOTS = 256;

    (void)hipMemsetAsync(hist, 0, (size_t)n * 8 * 8, stream);
    (void)hipMemsetAsync(partial, 0, (size_t)NB_SLOTS * 128 * 4, stream);

    int tb = 256;
    {
        int nF4  = n * F / 4;
        int WTOT = 2 * F * HC1 + 2 * HC1 * HC2 + 2 * HC1 + 2 * HC2;
        int total = E + nF4 + WTOT;
        fused_prep<<<(total + tb - 1) / tb, tb, 0, stream>>>(
            ei, ea, hist, E, x, xb, nF4,
            W1l, W1r, W2l, W2r, b1l, b1r, b2l, b2r,
            Wt1, Wt2, b1cat, b2cat, F, HC1, HC2);
    }
    scan_a<<<B, 256, 0, stream>>>(hist, bsum, n);
    scan_c<<<B, 256, 0, stream>>>(hist, bsum, row_ptr, wptr, ea_loop, n, B);
    edge_scatter<<<(E + tb - 1) / tb, tb, 0, stream>>>(ei, ea, wptr, spk, E);

    // layer 1: merged GEMM [n,128]@[128,512] -> dense xl1 | xr1 (fp8)
    {
        dim3 grid((n + 63) / 64, (2 * HC1) / 64);
        gemm_bf16<true><<<grid, 256, 0, stream>>>(xb, Wt1, b1cat, xl1, xr1, HC1, n, 2 * HC1, F);
    }
    gat_agg<256, 32, 0><<<(n + 3) / 4, 256, 0, stream>>>(
        xl1, xr1, We1, att1, bias1, row_ptr, spk, ea_loop, h1, n);

    // layer 2: merged GEMM [n,256]@[256,256] -> dense xl2 | xr2 (fp8)
    {
        dim3 grid((n + 63) / 64, (2 * HC2) / 64);
        gemm_bf16<true><<<grid, 256, 0, stream>>>(h1, Wt2, b2cat, xl2, xr2, HC2, n, 2 * HC2, HC1);
    }
    // layer-2 gat with fused pooling (LDS block-reduce + per-block atomics)
    gat_agg<128, 128, 1><<<(n + 3) / 4, 256, 0, stream>>>(
        xl2, xr2, We2, att2, bias2, row_ptr, spk, ea_loop, partial, n);

    pool_final<<<1, 1024, 0, stream>>>(partial, NB_SLOTS, alpha, out, n);
}

// Round 13
// 258.608 us; speedup vs baseline: 1.1400x; 1.0632x over previous
//
#include <hip/hip_runtime.h>
#include <math.h>

#define NEG_SLOPE 0.2f
#define LOG2E 1.4426950408889634f

typedef __attribute__((ext_vector_type(8))) short short8;   // 8 bf16 (4 VGPRs)
typedef __attribute__((ext_vector_type(4))) float f32x4;
typedef __attribute__((ext_vector_type(2))) float v2f;

__device__ __forceinline__ int imin(int a, int b) { return a < b ? a : b; }

__device__ __forceinline__ unsigned int f2bf(float f) {
    unsigned int u = __float_as_uint(f);
    return (u + 0x7fffu + ((u >> 16) & 1u)) >> 16;   // RNE
}
__device__ __forceinline__ float fast_exp2(float x) {
#if __has_builtin(__builtin_amdgcn_exp2f)
    return __builtin_amdgcn_exp2f(x);
#else
    return exp2f(x);
#endif
}
// fp8 (OCP e4m3 on gfx950) hardware pack/unpack
__device__ __forceinline__ unsigned char f2fp8(float v) {
    return (unsigned char)(__builtin_amdgcn_cvt_pk_fp8_f32(v, v, 0, false) & 0xff);
}
template <int CTRL>
__device__ __forceinline__ float dpp_add(float v) {
    int t = __builtin_amdgcn_update_dpp(0, __float_as_int(v), CTRL, 0xF, 0xF, true);
    return v + __int_as_float(t);
}
// gfx90a+ packed-FP32 VALU (2 channels / instruction) — hipcc scalarizes
// float2 arithmetic, so force the pk forms via asm.
__device__ __forceinline__ v2f pk_fma(v2f a, v2f b, v2f c) {
    v2f d;
    asm("v_pk_fma_f32 %0, %1, %2, %3" : "=v"(d) : "v"(a), "v"(b), "v"(c));
    return d;
}
__device__ __forceinline__ v2f pk_add(v2f a, v2f b) {
    v2f d;
    asm("v_pk_add_f32 %0, %1, %2" : "=v"(d) : "v"(a), "v"(b));
    return d;
}

// ---------------------------------------------------------------------------
// Fused prep kernel: three disjoint index ranges in one launch.
//  [0, E)            : packed histogram (64-bit atomic, 64B-padded slots)
//  [E, E+nF4)        : x fp32 -> bf16 (vec4)
//  [E+nF4, ..+WTOT)  : weight transposes -> bf16 + bias concats
// ---------------------------------------------------------------------------
__global__ void fused_prep(const int* __restrict__ ei, const float* __restrict__ ea,
                           unsigned long long* __restrict__ hist, int E,
                           const float* __restrict__ x, unsigned short* __restrict__ xb, int nF4,
                           const float* __restrict__ W1l, const float* __restrict__ W1r,
                           const float* __restrict__ W2l, const float* __restrict__ W2r,
                           const float* __restrict__ b1l, const float* __restrict__ b1r,
                           const float* __restrict__ b2l, const float* __restrict__ b2r,
                           unsigned short* __restrict__ Wt1, unsigned short* __restrict__ Wt2,
                           float* __restrict__ b1cat, float* __restrict__ b2cat,
                           int F, int HC1, int HC2) {
    int i = blockIdx.x * blockDim.x + threadIdx.x;
    if (i < E) {
        int d = ei[E + i];
        long long fx = (long long)__float2int_rn(ea[i] * 65536.0f);
        unsigned long long v = ((unsigned long long)fx << 32) | 1ull;
        atomicAdd(&hist[(size_t)d * 8], v);
        return;
    }
    int j = i - E;
    if (j < nF4) {
        float4 v = ((const float4*)x)[j];
        uint2 r;
        r.x = f2bf(v.x) | (f2bf(v.y) << 16);
        r.y = f2bf(v.z) | (f2bf(v.w) << 16);
        ((uint2*)xb)[j] = r;
        return;
    }
    int k = j - nF4;
    int S1 = F * HC1, S2 = HC1 * HC2;
    if (k < S1) {
        int kk = k / HC1, nn = k - kk * HC1;
        Wt1[(size_t)nn * F + kk] = (unsigned short)f2bf(W1l[k]);
    } else if (k < 2 * S1) {
        int m = k - S1;
        int kk = m / HC1, nn = m - kk * HC1;
        Wt1[(size_t)(HC1 + nn) * F + kk] = (unsigned short)f2bf(W1r[m]);
    } else if (k < 2 * S1 + S2) {
        int m = k - 2 * S1;
        int kk = m / HC2, nn = m - kk * HC2;
        Wt2[(size_t)nn * HC1 + kk] = (unsigned short)f2bf(W2l[m]);
    } else if (k < 2 * S1 + 2 * S2) {
        int m = k - 2 * S1 - S2;
        int kk = m / HC2, nn = m - kk * HC2;
        Wt2[(size_t)(HC2 + nn) * HC1 + kk] = (unsigned short)f2bf(W2r[m]);
    } else if (k < 2 * S1 + 2 * S2 + 2 * HC1) {
        int m = k - 2 * S1 - 2 * S2;
        b1cat[m] = (m < HC1) ? b1l[m] : b1r[m - HC1];
    } else if (k < 2 * S1 + 2 * S2 + 2 * HC1 + 2 * HC2) {
        int m = k - 2 * S1 - 2 * S2 - 2 * HC1;
        b2cat[m] = (m < HC2) ? b2l[m] : b2r[m - HC2];
    }
}

// ---------------------------------------------------------------------------
// 2-phase parallel scan over hist (padded stride 8): scan_a computes raw
// block sums; scan_c derives its own prefix from bsum in-wave (scan_b folded).
// ---------------------------------------------------------------------------
__global__ void scan_a(const unsigned long long* __restrict__ hist, int* __restrict__ bsum, int n) {
    __shared__ int wred[4];
    int base = blockIdx.x * 1024;
    int tid = threadIdx.x;
    int s = 0;
#pragma unroll
    for (int k = 0; k < 4; ++k) {
        int i = base + tid + k * 256;
        if (i < n) s += (int)(hist[(size_t)i * 8] & 0xffffffffull);
    }
#pragma unroll
    for (int off = 32; off > 0; off >>= 1) s += __shfl_xor(s, off, 64);
    if ((tid & 63) == 0) wred[tid >> 6] = s;
    __syncthreads();
    if (tid == 0) bsum[blockIdx.x] = wred[0] + wred[1] + wred[2] + wred[3];
}

__global__ void scan_c(const unsigned long long* __restrict__ hist,
                       const int* __restrict__ bsum, int* __restrict__ row_ptr,
                       int* __restrict__ wptr_pad, float* __restrict__ ea_loop,
                       int n, int B) {
    __shared__ int wtot[4];
    __shared__ int sh_base;
    int tid = threadIdx.x;
    int wid = tid >> 6, lane = tid & 63;
    int i0 = blockIdx.x * 1024 + tid * 4;
    int dcnt[4]; float esum[4];
#pragma unroll
    for (int k = 0; k < 4; ++k) {
        if (i0 + k < n) {
            unsigned long long h = hist[(size_t)(i0 + k) * 8];
            dcnt[k] = (int)(h & 0xffffffffull);
            esum[k] = (float)((int)(h >> 32)) * (1.0f / 65536.0f);
        } else { dcnt[k] = 0; esum[k] = 0.0f; }
    }
    int tsum = dcnt[0] + dcnt[1] + dcnt[2] + dcnt[3];
    int s = tsum;
#pragma unroll
    for (int off = 1; off < 64; off <<= 1) {
        int t = __shfl_up(s, off, 64);
        if (lane >= off) s += t;
    }
    if (lane == 63) wtot[wid] = s;
    // wave 0: block prefix (sum of bsum[0..blockIdx)) and grand total
    if (tid < 64) {
        int v   = (tid < B) ? bsum[tid] : 0;
        int pre = (tid < (int)blockIdx.x) ? v : 0;
        int tot = v;
#pragma unroll
        for (int off = 32; off > 0; off >>= 1) {
            pre += __shfl_xor(pre, off, 64);
            tot += __shfl_xor(tot, off, 64);
        }
        if (tid == 0) {
            sh_base = pre;
            if (blockIdx.x == 0) row_ptr[n] = tot;
        }
    }
    __syncthreads();
    int wpre = 0;
#pragma unroll
    for (int k = 0; k < 4; ++k) if (k < wid) wpre += wtot[k];
    int pre = sh_base + wpre + (s - tsum);
    if (i0 < n) {
        int4 e;
        e.x = pre;
        e.y = pre + dcnt[0];
        e.z = e.y + dcnt[1];
        e.w = e.z + dcnt[2];
        *(int4*)(row_ptr + i0) = e;
        int ev[4] = { e.x, e.y, e.z, e.w };
        float4 el;
        el.x = esum[0] / fmaxf((float)dcnt[0], 1.0f);
        el.y = esum[1] / fmaxf((float)dcnt[1], 1.0f);
        el.z = esum[2] / fmaxf((float)dcnt[2], 1.0f);
        el.w = esum[3] / fmaxf((float)dcnt[3], 1.0f);
        *(float4*)(ea_loop + i0) = el;
#pragma unroll
        for (int k = 0; k < 4; ++k) wptr_pad[(size_t)(i0 + k) * 16] = ev[k];
    }
}

// ---------------------------------------------------------------------------
// HYBRID: edge_scatter + layer-1 GEMM in ONE launch (they are independent:
// scatter needs scan_c, GEMM needs only fused_prep).  Block-parity
// interleave co-schedules the atomic/latency-bound scatter waves with the
// MFMA/LDS-bound GEMM waves on every CU (m114: separate pipes overlap,
// time ~= max not sum).  Scatter blocks return before any barrier
// (uniform per block).  Disjoint memory: scatter writes wptr/spk; GEMM
// reads xb/Wt1, writes xl1/xr1.
//  NS scatter blocks (256 thr, e = sb*256+tid)
//  GB gemm blocks    (64x64 tile; idx -> bx = idx/GY, by = idx%GY)
// grid = 2*min(NS,GB) + |NS-GB|; parity split while both remain.
// ---------------------------------------------------------------------------
__global__ void __launch_bounds__(256)
scat_gemm1(const int* __restrict__ ei, const float* __restrict__ ea,
           int* __restrict__ wptr_pad, int2* __restrict__ spk, int E, int NS,
           const unsigned short* __restrict__ A, const unsigned short* __restrict__ Bt,
           const float* __restrict__ bias, unsigned char* __restrict__ Cv,
           unsigned char* __restrict__ Cv2, int split, int M, int N, int K, int GB) {
    __shared__ __attribute__((aligned(16))) unsigned short As[64 * 40];
    __shared__ __attribute__((aligned(16))) unsigned short Bs[64 * 40];
    int bid = blockIdx.x;
    int nmin = imin(NS, GB);
    bool is_scat;
    int idx;
    if (bid < 2 * nmin) { is_scat = !(bid & 1); idx = bid >> 1; }
    else                { idx = bid - nmin;     is_scat = (NS > GB); }

    if (is_scat) {
        int e = idx * 256 + threadIdx.x;
        if (e < E) {
            int d = ei[E + e];
            int pos = atomicAdd(&wptr_pad[(size_t)d * 16], 1);
            spk[pos] = make_int2(ei[e], __float_as_int(ea[e]));
        }
        return;
    }

    // ---- GEMM role ----
    int GY = N >> 6;
    int bx = idx / GY, by = idx - bx * GY;
    int tid  = threadIdx.x;
    int wave = tid >> 6, lane = tid & 63;
    int m0 = bx * 64, n0 = by * 64;
    int row = tid >> 2, kg = (tid & 3) * 8;

    f32x4 acc[4] = {};
    for (int kk = 0; kk < K; kk += 32) {
        int gm = m0 + row;
        uint4 av;
        if (gm < M) av = *(const uint4*)(A + (size_t)gm * K + kk + kg);
        else        av = make_uint4(0, 0, 0, 0);
        *(uint4*)&As[row * 40 + kg] = av;
        uint4 bv = *(const uint4*)(Bt + (size_t)(n0 + row) * K + kk + kg);
        *(uint4*)&Bs[row * 40 + kg] = bv;
        __syncthreads();
        short8 a = *(const short8*)&As[(wave * 16 + (lane & 15)) * 40 + (lane >> 4) * 8];
#pragma unroll
        for (int g = 0; g < 4; ++g) {
            short8 b = *(const short8*)&Bs[(g * 16 + (lane & 15)) * 40 + (lane >> 4) * 8];
            acc[g] = __builtin_amdgcn_mfma_f32_16x16x32_bf16(a, b, acc[g], 0, 0, 0);
        }
        __syncthreads();
    }
#pragma unroll
    for (int g = 0; g < 4; ++g) {
        int col = n0 + g * 16 + (lane & 15);
        float bs = bias[col];
#pragma unroll
        for (int r = 0; r < 4; ++r) {
            int grow = m0 + wave * 16 + (lane >> 4) * 4 + r;
            if (grow < M) {
                unsigned char c = f2fp8(acc[g][r] + bs);
                if (col < split) Cv[(size_t)grow * split + col] = c;
                else             Cv2[(size_t)grow * split + (col - split)] = c;
            }
        }
    }
}

// ---------------------------------------------------------------------------
// bf16 MFMA GEMM + bias (B pre-transposed), 64x64 tile, BK=32 (layer 2).
// OUT_FP8: epilogue packs to fp8 and splits cols into xl / xr dense tables.
// ---------------------------------------------------------------------------
template <bool OUT_FP8>
__global__ void __launch_bounds__(256)
gemm_bf16(const unsigned short* __restrict__ A, const unsigned short* __restrict__ Bt,
          const float* __restrict__ bias, void* __restrict__ Cv, void* __restrict__ Cv2,
          int split, int M, int N, int K) {
    __shared__ __attribute__((aligned(16))) unsigned short As[64 * 40];
    __shared__ __attribute__((aligned(16))) unsigned short Bs[64 * 40];
    int tid  = threadIdx.x;
    int wave = tid >> 6, lane = tid & 63;
    int m0 = blockIdx.x * 64, n0 = blockIdx.y * 64;
    int row = tid >> 2, kg = (tid & 3) * 8;

    f32x4 acc[4] = {};
    for (int kk = 0; kk < K; kk += 32) {
        int gm = m0 + row;
        uint4 av;
        if (gm < M) av = *(const uint4*)(A + (size_t)gm * K + kk + kg);
        else        av = make_uint4(0, 0, 0, 0);
        *(uint4*)&As[row * 40 + kg] = av;
        uint4 bv = *(const uint4*)(Bt + (size_t)(n0 + row) * K + kk + kg);
        *(uint4*)&Bs[row * 40 + kg] = bv;
        __syncthreads();
        short8 a = *(const short8*)&As[(wave * 16 + (lane & 15)) * 40 + (lane >> 4) * 8];
#pragma unroll
        for (int g = 0; g < 4; ++g) {
            short8 b = *(const short8*)&Bs[(g * 16 + (lane & 15)) * 40 + (lane >> 4) * 8];
            acc[g] = __builtin_amdgcn_mfma_f32_16x16x32_bf16(a, b, acc[g], 0, 0, 0);
        }
        __syncthreads();
    }
#pragma unroll
    for (int g = 0; g < 4; ++g) {
        int col = n0 + g * 16 + (lane & 15);
        float bs = bias[col];
#pragma unroll
        for (int r = 0; r < 4; ++r) {
            int grow = m0 + wave * 16 + (lane >> 4) * 4 + r;
            if (grow < M) {
                float val = acc[g][r] + bs;
                if constexpr (OUT_FP8) {
                    unsigned char c = f2fp8(val);
                    if (col < split) ((unsigned char*)Cv)[(size_t)grow * split + col] = c;
                    else             ((unsigned char*)Cv2)[(size_t)grow * split + (col - split)] = c;
                } else {
                    ((unsigned short*)Cv)[(size_t)grow * N + col] = (unsigned short)f2bf(val);
                }
            }
        }
    }
}

// ---------------------------------------------------------------------------
// helpers for gat_agg (fp8 gather, packed-f32 math)
// ---------------------------------------------------------------------------
template <int NV>
__device__ __forceinline__ void unp1(unsigned int u, v2f* xf) {
    xf[0] = __builtin_amdgcn_cvt_pk_f32_fp8(u, false);
    if constexpr (NV == 4) xf[1] = __builtin_amdgcn_cvt_pk_f32_fp8(u, true);
}
// reduction over G consecutive lanes (G-aligned groups), full 64-lane wave
template <int G>
__device__ __forceinline__ float grp_reduce(float vs) {
    vs = dpp_add<0xB1>(vs);                               // xor 1
    if constexpr (G >= 4)  vs = dpp_add<0x4E>(vs);        // xor 2
    if constexpr (G >= 8)  vs = dpp_add<0x141>(vs);       // xor 4 (row_half_mirror)
    if constexpr (G >= 16) vs = dpp_add<0x140>(vs);       // xor 8 (row_mirror)
    if constexpr (G >= 32) {                              // xor 16
        int t = __builtin_amdgcn_ds_swizzle(__float_as_int(vs), 0x401F);
        vs += __int_as_float(t);
    }
    if constexpr (G >= 64) vs += __shfl_xor(vs, 32, 64);  // xor 32
    return vs;
}

// ---------------------------------------------------------------------------
// fused GATv2 gather(fp8) + score + softmax + aggregate + relu.
// ONE EDGE PER FULL WAVE (64 lanes x NV=HC/64 channels), depth-6 mov-free
// register gather pipeline, dense xl/xr split tables (best measured config;
// R2-R11 ledger: the gather-softmax phase is pinned at ~41-48us/layer by
// crossing issue and latency floors — structural plateau).
// OUT_MODE 0: dense bf16 rows.
// OUT_MODE 1: LDS block-reduction (4 waves) then 128 atomics per BLOCK.
// ---------------------------------------------------------------------------
template <int HC, int C, int OUT_MODE>
__global__ void __launch_bounds__(256)
gat_agg(const unsigned char* __restrict__ xl, const unsigned char* __restrict__ xr,
        const float* __restrict__ We, const float* __restrict__ att,
        const float* __restrict__ bias,
        const int* __restrict__ row_ptr, const int2* __restrict__ spk,
        const float* __restrict__ ea_loop,
        void* __restrict__ out, int n) {
    constexpr int NV = HC / 64;      // channels (bytes) per lane, full-wave row
    constexpr int NG = (NV + 1) / 2; // v2f groups per lane (NV=4 -> 2, NV=2 -> 1)
    constexpr int G  = C / NV;       // lanes per head
    constexpr int SHIFT = (HC == 256) ? 8 : 7;   // dense xl row stride
    constexpr float K23 = 2.0f / 3.0f;
    __shared__ float red[4][128];    // OUT_MODE 1 block pooling reduction
    int wave = threadIdx.x >> 6;
    int lane = threadIdx.x & 63;
    int node = blockIdx.x * 4 + wave;
    bool active = node < n;
    if (OUT_MODE == 0 && !active) return;
    unsigned int lo = (unsigned int)lane * NV;   // channel/byte offset

    float vout[NV];
#pragma unroll
    for (int j = 0; j < NV; ++j) vout[j] = 0.0f;

    if (active) {
        auto ldd = [&](const unsigned char* base, unsigned int off) -> unsigned int {
            if constexpr (NV == 4) return *(const unsigned int*)(base + off);
            else                   return (unsigned int)(*(const unsigned short*)(base + off));
        };
        auto gat = [&](int s) -> unsigned int {
            return ldd(xl, ((unsigned int)s << SHIFT) + lo);
        };
        auto W = [&](int2 s) -> float { return __int_as_float(s.y); };

        v2f xr2[NG], We2[NG], att62[NG], o2[NG];
        {
            v2f tmp[NG];
            unp1<NV>(ldd(xr, ((unsigned int)node << SHIFT) + lo), tmp);
#pragma unroll
            for (int g = 0; g < NG; ++g) xr2[g] = tmp[g];
        }
#pragma unroll
        for (int g = 0; g < NG; ++g) {
            We2[g]   = *(const v2f*)(We  + lo + 2 * g);
            v2f a    = *(const v2f*)(att + lo + 2 * g);
            att62[g] = a * (0.6f * LOG2E);
            o2[g]    = v2f{0.0f, 0.0f};
        }
        float l = 0.0f;

        int start = __builtin_amdgcn_readfirstlane(row_ptr[node]);
        int end   = __builtin_amdgcn_readfirstlane(row_ptr[node + 1]);
        float ea_l = ea_loop[node];

        auto process = [&](unsigned int du, float w) {
            v2f xf[NG];
            unp1<NV>(du, xf);
            v2f w2 = {w, w};
            v2f vs6 = {0.0f, 0.0f};
            float vs4 = 0.0f;
#pragma unroll
            for (int g = 0; g < NG; ++g) {
                v2f t  = pk_fma(w2, We2[g], xr2[g]);     // xr + w*We
                v2f mm = pk_add(xf[g], t);               // xl[src] + xr + w*We
                vs6 = pk_fma(att62[g], mm, vs6);
                vs4 = fmaf(fabsf(mm.x), att62[g].x, vs4);   // abs = free modifier
                vs4 = fmaf(fabsf(mm.y), att62[g].y, vs4);
            }
            float vs = fmaf(K23, vs4, vs6.x + vs6.y);
            vs = grp_reduce<G>(vs);
            float pr = fast_exp2(vs);
            l += pr;
            v2f pr2 = {pr, pr};
#pragma unroll
            for (int g = 0; g < NG; ++g) o2[g] = pk_fma(xf[g], pr2, o2[g]);
        };

        // ---- self-loop edge ----
        process(gat(node), ea_l);

        // ---- real edges: 6-deep mov-free gather pipeline ----
        int cnt = end - start;
        const int2* q = spk + start;   // wave-uniform meta per edge

        if (cnt >= 6) {
            int2 t;
            t = q[0]; unsigned int g0 = gat(t.x); float w0 = W(t);
            t = q[1]; unsigned int g1 = gat(t.x); float w1 = W(t);
            t = q[2]; unsigned int g2 = gat(t.x); float w2 = W(t);
            t = q[3]; unsigned int g3 = gat(t.x); float w3 = W(t);
            t = q[4]; unsigned int g4 = gat(t.x); float w4 = W(t);
            t = q[5]; unsigned int g5 = gat(t.x); float w5 = W(t);
            int p = 0;
            // invariant at loop top: g0..g5 / w0..w5 hold edges p..p+5
            for (; p + 12 <= cnt; p += 6) {
                process(g0, w0); t = q[p + 6];  g0 = gat(t.x); w0 = W(t);
                process(g1, w1); t = q[p + 7];  g1 = gat(t.x); w1 = W(t);
                process(g2, w2); t = q[p + 8];  g2 = gat(t.x); w2 = W(t);
                process(g3, w3); t = q[p + 9];  g3 = gat(t.x); w3 = W(t);
                process(g4, w4); t = q[p + 10]; g4 = gat(t.x); w4 = W(t);
                process(g5, w5); t = q[p + 11]; g5 = gat(t.x); w5 = W(t);
            }
            // r = cnt - p in [6, 11]
            process(g0, w0); process(g1, w1); process(g2, w2);
            process(g3, w3); process(g4, w4); process(g5, w5);
            for (int k = p + 6; k < cnt; ++k) {
                t = q[k];
                process(gat(t.x), W(t));
            }
        } else {
            for (int k = 0; k < cnt; ++k) {
                int2 t = q[k];
                process(gat(t.x), W(t));
            }
        }

        // ---- epilogue: every lane owns its NV channels and full head denom ----
        float inv = 1.0f / (l + 1e-16f);
#pragma unroll
        for (int g = 0; g < NG; ++g) {
            v2f b = *(const v2f*)(bias + lo + 2 * g);
            vout[2 * g]     = fmaxf(o2[g].x * inv + b.x, 0.0f);
            vout[2 * g + 1] = fmaxf(o2[g].y * inv + b.y, 0.0f);
        }
        if constexpr (OUT_MODE == 0) {
            unsigned short* op = (unsigned short*)out + (size_t)node * HC + lo;
            if constexpr (NV == 4) {
                uint2 t;
                t.x = f2bf(vout[0]) | (f2bf(vout[1]) << 16);
                t.y = f2bf(vout[2]) | (f2bf(vout[3]) << 16);
                *(uint2*)op = t;
            } else {
                *(unsigned int*)op = f2bf(vout[0]) | (f2bf(vout[1]) << 16);
            }
        }
    }

    if constexpr (OUT_MODE == 1) {
        // block-level pooling reduction: 4 waves -> LDS -> one atomic pass
#pragma unroll
        for (int j = 0; j < NV; ++j) red[wave][lo + j] = vout[j];
        __syncthreads();
        if (wave == 0) {
            int c = lane;   // channels c and c+64
            float a = red[0][c] + red[1][c] + red[2][c] + red[3][c];
            float b = red[0][c + 64] + red[1][c + 64] + red[2][c + 64] + red[3][c + 64];
            float* pacc = (float*)out + (size_t)(blockIdx.x & 255) * 128;
            atomicAdd(&pacc[c], a);
            atomicAdd(&pacc[c + 64], b);
        }
    }
}

// ---------------------------------------------------------------------------
// finish pooling, softmax over 128, sigmoid(alpha). 1024 threads.
// ---------------------------------------------------------------------------
__global__ void __launch_bounds__(1024)
pool_final(const float* __restrict__ partial, int nb,
           const float* __restrict__ alpha_in,
           float* __restrict__ out, int n) {
    __shared__ float acc[8][128];
    __shared__ float red[4];
    int t = threadIdx.x & 127;        // column
    int g = threadIdx.x >> 7;         // group 0..7
    float s = 0.0f;
    for (int b = g; b < nb; b += 8) s += partial[b * 128 + t];
    acc[g][t] = s;
    __syncthreads();
    if (threadIdx.x < 128) {
        float tot = 0.0f;
#pragma unroll
        for (int k = 0; k < 8; ++k) tot += acc[k][t];
        float mean = tot / (float)n;
        float mx = mean;
#pragma unroll
        for (int off = 32; off > 0; off >>= 1) mx = fmaxf(mx, __shfl_xor(mx, off, 64));
        if ((t & 63) == 0) red[t >> 6] = mx;
        __syncthreads();
        mx = fmaxf(red[0], red[1]);
        float ex = __expf(mean - mx);
        float sm = ex;
#pragma unroll
        for (int off = 32; off > 0; off >>= 1) sm += __shfl_xor(sm, off, 64);
        if ((t & 63) == 0) red[2 + (t >> 6)] = sm;
        __syncthreads();
        sm = red[2] + red[3];
        out[t] = ex / sm;
        if (t == 0) out[128] = 1.0f / (1.0f + __expf(-alpha_in[0]));
    }
}

// ---------------------------------------------------------------------------
extern "C" void kernel_launch(void* const* d_in, const int* in_sizes, int n_in,
                              void* d_out, int out_size, void* d_ws, size_t ws_size,
                              hipStream_t stream) {
    const float* x    = (const float*)d_in[0];
    const int*   ei   = (const int*)d_in[1];
    const float* ea   = (const float*)d_in[2];
    const float* W1l  = (const float*)d_in[3];
    const float* b1l  = (const float*)d_in[4];
    const float* W1r  = (const float*)d_in[5];
    const float* b1r  = (const float*)d_in[6];
    const float* We1  = (const float*)d_in[7];
    const float* att1 = (const float*)d_in[8];
    const float* bias1= (const float*)d_in[9];
    const float* W2l  = (const float*)d_in[10];
    const float* b2l  = (const float*)d_in[11];
    const float* W2r  = (const float*)d_in[12];
    const float* b2r  = (const float*)d_in[13];
    const float* We2  = (const float*)d_in[14];
    const float* att2 = (const float*)d_in[15];
    const float* bias2= (const float*)d_in[16];
    const float* alpha= (const float*)d_in[17];
    float* out = (float*)d_out;

    const int F = 128, HC1 = 256, HC2 = 128;
    const int n = in_sizes[0] / F;       // 20000
    const int E = in_sizes[1] / 2;       // 640000
    const int B = (n + 1023) / 1024;     // scan blocks

    char* ws = (char*)d_ws;
    size_t off = 0;
    auto alloc = [&](size_t bytes) { size_t p = off; off += (bytes + 255) & ~(size_t)255; return p; };

    unsigned long long* hist = (unsigned long long*)(ws + alloc((size_t)n * 8 * 8));  // padded x8
    int*   row_ptr = (int*)  (ws + alloc((size_t)(n + 1) * 4));
    int*   wptr    = (int*)  (ws + alloc((size_t)n * 16 * 4));                        // padded x16
    float* ea_loop = (float*)(ws + alloc((size_t)n * 4));
    int*   bsum    = (int*)  (ws + alloc(64 * 4));
    int2*  spk     = (int2*) (ws + alloc((size_t)E * 8));
    unsigned short* xb   = (unsigned short*)(ws + alloc((size_t)n * F * 2));
    unsigned short* Wt1  = (unsigned short*)(ws + alloc((size_t)F * (2 * HC1) * 2));
    unsigned short* Wt2  = (unsigned short*)(ws + alloc((size_t)HC1 * (2 * HC2) * 2));
    float* b1cat   = (float*)(ws + alloc((size_t)2 * HC1 * 4));
    float* b2cat   = (float*)(ws + alloc((size_t)2 * HC2 * 4));
    unsigned char* xl1 = (unsigned char*)(ws + alloc((size_t)n * HC1));   // dense fp8 xl table
    unsigned char* xr1 = (unsigned char*)(ws + alloc((size_t)n * HC1));   // dense fp8 xr table
    unsigned short* h1  = (unsigned short*)(ws + alloc((size_t)n * HC1 * 2));  // bf16
    float* partial = (float*)(ws + alloc((size_t)256 * 128 * 4));
    unsigned char* xl2 = xl1;   // layer-2 tables alias layer-1 (dead by then)
    unsigned char* xr2 = xr1;
    const int NB_SLOTS = 256;

    (void)hipMemsetAsync(hist, 0, (size_t)n * 8 * 8, stream);
    (void)hipMemsetAsync(partial, 0, (size_t)NB_SLOTS * 128 * 4, stream);

    int tb = 256;
    {
        int nF4  = n * F / 4;
        int WTOT = 2 * F * HC1 + 2 * HC1 * HC2 + 2 * HC1 + 2 * HC2;
        int total = E + nF4 + WTOT;
        fused_prep<<<(total + tb - 1) / tb, tb, 0, stream>>>(
            ei, ea, hist, E, x, xb, nF4,
            W1l, W1r, W2l, W2r, b1l, b1r, b2l, b2r,
            Wt1, Wt2, b1cat, b2cat, F, HC1, HC2);
    }
    scan_a<<<B, 256, 0, stream>>>(hist, bsum, n);
    scan_c<<<B, 256, 0, stream>>>(hist, bsum, row_ptr, wptr, ea_loop, n, B);

    // HYBRID: edge_scatter + layer-1 GEMM co-scheduled in one launch
    {
        int NS = (E + 255) / 256;                         // 2500 scatter blocks
        int GB = ((n + 63) / 64) * ((2 * HC1) / 64);      // 2504 gemm blocks
        int nmin = NS < GB ? NS : GB;
        int grid = 2 * nmin + (NS > GB ? NS - GB : GB - NS);
        scat_gemm1<<<grid, 256, 0, stream>>>(
            ei, ea, wptr, spk, E, NS,
            xb, Wt1, b1cat, xl1, xr1, HC1, n, 2 * HC1, F, GB);
    }
    gat_agg<256, 32, 0><<<(n + 3) / 4, 256, 0, stream>>>(
        xl1, xr1, We1, att1, bias1, row_ptr, spk, ea_loop, h1, n);

    // layer 2: merged GEMM [n,256]@[256,256] -> dense xl2 | xr2 (fp8)
    {
        dim3 grid((n + 63) / 64, (2 * HC2) / 64);
        gemm_bf16<true><<<grid, 256, 0, stream>>>(h1, Wt2, b2cat, xl2, xr2, HC2, n, 2 * HC2, HC1);
    }
    // layer-2 gat with fused pooling (LDS block-reduce + per-block atomics)
    gat_agg<128, 128, 1><<<(n + 3) / 4, 256, 0, stream>>>(
        xl2, xr2, We2, att2, bias2, row_ptr, spk, ea_loop, partial, n);

    pool_final<<<1, 1024, 0, stream>>>(partial, NB_SLOTS, alpha, out, n);
}

// Round 14
// 257.870 us; speedup vs baseline: 1.1433x; 1.0029x over previous
//
#include <hip/hip_runtime.h>
#include <math.h>

#define NEG_SLOPE 0.2f
#define LOG2E 1.4426950408889634f

typedef __attribute__((ext_vector_type(8))) short short8;   // 8 bf16 (4 VGPRs)
typedef __attribute__((ext_vector_type(4))) float f32x4;
typedef __attribute__((ext_vector_type(2))) float v2f;

__device__ __forceinline__ int imin(int a, int b) { return a < b ? a : b; }

__device__ __forceinline__ unsigned int f2bf(float f) {
    unsigned int u = __float_as_uint(f);
    return (u + 0x7fffu + ((u >> 16) & 1u)) >> 16;   // RNE
}
__device__ __forceinline__ float fast_exp2(float x) {
#if __has_builtin(__builtin_amdgcn_exp2f)
    return __builtin_amdgcn_exp2f(x);
#else
    return exp2f(x);
#endif
}
// fp8 (OCP e4m3 on gfx950) hardware pack/unpack
__device__ __forceinline__ unsigned char f2fp8(float v) {
    return (unsigned char)(__builtin_amdgcn_cvt_pk_fp8_f32(v, v, 0, false) & 0xff);
}
template <int CTRL>
__device__ __forceinline__ float dpp_add(float v) {
    int t = __builtin_amdgcn_update_dpp(0, __float_as_int(v), CTRL, 0xF, 0xF, true);
    return v + __int_as_float(t);
}
// gfx90a+ packed-FP32 VALU (2 channels / instruction) — hipcc scalarizes
// float2 arithmetic, so force the pk forms via asm.
__device__ __forceinline__ v2f pk_fma(v2f a, v2f b, v2f c) {
    v2f d;
    asm("v_pk_fma_f32 %0, %1, %2, %3" : "=v"(d) : "v"(a), "v"(b), "v"(c));
    return d;
}
__device__ __forceinline__ v2f pk_add(v2f a, v2f b) {
    v2f d;
    asm("v_pk_add_f32 %0, %1, %2" : "=v"(d) : "v"(a), "v"(b));
    return d;
}

// ---------------------------------------------------------------------------
// Fused prep kernel: three disjoint index ranges in one launch.
// ---------------------------------------------------------------------------
__global__ void fused_prep(const int* __restrict__ ei, const float* __restrict__ ea,
                           unsigned long long* __restrict__ hist, int E,
                           const float* __restrict__ x, unsigned short* __restrict__ xb, int nF4,
                           const float* __restrict__ W1l, const float* __restrict__ W1r,
                           const float* __restrict__ W2l, const float* __restrict__ W2r,
                           const float* __restrict__ b1l, const float* __restrict__ b1r,
                           const float* __restrict__ b2l, const float* __restrict__ b2r,
                           unsigned short* __restrict__ Wt1, unsigned short* __restrict__ Wt2,
                           float* __restrict__ b1cat, float* __restrict__ b2cat,
                           int F, int HC1, int HC2) {
    int i = blockIdx.x * blockDim.x + threadIdx.x;
    if (i < E) {
        int d = ei[E + i];
        long long fx = (long long)__float2int_rn(ea[i] * 65536.0f);
        unsigned long long v = ((unsigned long long)fx << 32) | 1ull;
        atomicAdd(&hist[(size_t)d * 8], v);
        return;
    }
    int j = i - E;
    if (j < nF4) {
        float4 v = ((const float4*)x)[j];
        uint2 r;
        r.x = f2bf(v.x) | (f2bf(v.y) << 16);
        r.y = f2bf(v.z) | (f2bf(v.w) << 16);
        ((uint2*)xb)[j] = r;
        return;
    }
    int k = j - nF4;
    int S1 = F * HC1, S2 = HC1 * HC2;
    if (k < S1) {
        int kk = k / HC1, nn = k - kk * HC1;
        Wt1[(size_t)nn * F + kk] = (unsigned short)f2bf(W1l[k]);
    } else if (k < 2 * S1) {
        int m = k - S1;
        int kk = m / HC1, nn = m - kk * HC1;
        Wt1[(size_t)(HC1 + nn) * F + kk] = (unsigned short)f2bf(W1r[m]);
    } else if (k < 2 * S1 + S2) {
        int m = k - 2 * S1;
        int kk = m / HC2, nn = m - kk * HC2;
        Wt2[(size_t)nn * HC1 + kk] = (unsigned short)f2bf(W2l[m]);
    } else if (k < 2 * S1 + 2 * S2) {
        int m = k - 2 * S1 - S2;
        int kk = m / HC2, nn = m - kk * HC2;
        Wt2[(size_t)(HC2 + nn) * HC1 + kk] = (unsigned short)f2bf(W2r[m]);
    } else if (k < 2 * S1 + 2 * S2 + 2 * HC1) {
        int m = k - 2 * S1 - 2 * S2;
        b1cat[m] = (m < HC1) ? b1l[m] : b1r[m - HC1];
    } else if (k < 2 * S1 + 2 * S2 + 2 * HC1 + 2 * HC2) {
        int m = k - 2 * S1 - 2 * S2 - 2 * HC1;
        b2cat[m] = (m < HC2) ? b2l[m] : b2r[m - HC2];
    }
}

// ---------------------------------------------------------------------------
// MERGED scan (replaces scan_a + scan_c): one launch, B<=20 blocks.
// Phase A: each block publishes its total via atomicExch (device-coherent),
// arrives on ctr, thread 0 spins until all B arrived (capacity-trivial
// co-residency: 20 blocks on 256 CUs).  Phase B: original scan_c, but bsum
// read back via atomic loads (cross-XCD-safe).  Phase A reuses phase B's
// hist loads — scan_a's whole 1.28MB read pass is eliminated.
// ---------------------------------------------------------------------------
__global__ void __launch_bounds__(256)
scan_fused(const unsigned long long* __restrict__ hist, int* __restrict__ bsum,
           int* __restrict__ ctr, int* __restrict__ row_ptr,
           int* __restrict__ wptr_pad, float* __restrict__ ea_loop,
           int n, int B) {
    __shared__ int wtot[4];
    __shared__ int sh_base;
    int tid = threadIdx.x;
    int wid = tid >> 6, lane = tid & 63;
    int i0 = blockIdx.x * 1024 + tid * 4;
    int dcnt[4]; float esum[4];
#pragma unroll
    for (int k = 0; k < 4; ++k) {
        if (i0 + k < n) {
            unsigned long long h = hist[(size_t)(i0 + k) * 8];
            dcnt[k] = (int)(h & 0xffffffffull);
            esum[k] = (float)((int)(h >> 32)) * (1.0f / 65536.0f);
        } else { dcnt[k] = 0; esum[k] = 0.0f; }
    }
    int tsum = dcnt[0] + dcnt[1] + dcnt[2] + dcnt[3];

    // ---- phase A: publish block total, grid barrier ----
    int bt = tsum;
#pragma unroll
    for (int off = 32; off > 0; off >>= 1) bt += __shfl_xor(bt, off, 64);
    if (lane == 0) wtot[wid] = bt;
    __syncthreads();
    if (tid == 0) {
        atomicExch(&bsum[blockIdx.x], wtot[0] + wtot[1] + wtot[2] + wtot[3]);
        __threadfence();
        atomicAdd(ctr, 1);
        while (atomicAdd(ctr, 0) < B) { }
    }
    __syncthreads();

    // ---- phase B: original scan_c logic ----
    int s = tsum;
#pragma unroll
    for (int off = 1; off < 64; off <<= 1) {
        int t = __shfl_up(s, off, 64);
        if (lane >= off) s += t;
    }
    if (lane == 63) wtot[wid] = s;
    if (tid < 64) {
        int v   = (tid < B) ? atomicAdd(&bsum[tid], 0) : 0;
        int pre = (tid < (int)blockIdx.x) ? v : 0;
        int tot = v;
#pragma unroll
        for (int off = 32; off > 0; off >>= 1) {
            pre += __shfl_xor(pre, off, 64);
            tot += __shfl_xor(tot, off, 64);
        }
        if (tid == 0) {
            sh_base = pre;
            if (blockIdx.x == 0) row_ptr[n] = tot;
        }
    }
    __syncthreads();
    int wpre = 0;
#pragma unroll
    for (int k = 0; k < 4; ++k) if (k < wid) wpre += wtot[k];
    int pre = sh_base + wpre + (s - tsum);
    if (i0 < n) {
        int4 e;
        e.x = pre;
        e.y = pre + dcnt[0];
        e.z = e.y + dcnt[1];
        e.w = e.z + dcnt[2];
        *(int4*)(row_ptr + i0) = e;
        int ev[4] = { e.x, e.y, e.z, e.w };
        float4 el;
        el.x = esum[0] / fmaxf((float)dcnt[0], 1.0f);
        el.y = esum[1] / fmaxf((float)dcnt[1], 1.0f);
        el.z = esum[2] / fmaxf((float)dcnt[2], 1.0f);
        el.w = esum[3] / fmaxf((float)dcnt[3], 1.0f);
        *(float4*)(ea_loop + i0) = el;
#pragma unroll
        for (int k = 0; k < 4; ++k) wptr_pad[(size_t)(i0 + k) * 16] = ev[k];
    }
}

// ---------------------------------------------------------------------------
// shared GEMM tile body: 64x64 tile, BK=64 staging (half the barrier drains
// of the old BK=32), fp8 split epilogue.  LDS stride 72 shorts (2-way bank
// aliasing on b128 ops = free per m136).
// ---------------------------------------------------------------------------
__device__ __forceinline__ void gemm_body(
    const unsigned short* __restrict__ A, const unsigned short* __restrict__ Bt,
    const float* __restrict__ bias, unsigned char* __restrict__ Cv,
    unsigned char* __restrict__ Cv2, int split, int M, int N, int K,
    int bx, int by, unsigned short* As, unsigned short* Bs) {
    int tid  = threadIdx.x;
    int wave = tid >> 6, lane = tid & 63;
    int m0 = bx * 64, n0 = by * 64;
    int row = tid >> 2, c2 = (tid & 3) * 16;

    f32x4 acc[4] = {};
    for (int kk = 0; kk < K; kk += 64) {
        int gm = m0 + row;
        uint4 av0, av1;
        if (gm < M) {
            av0 = *(const uint4*)(A + (size_t)gm * K + kk + c2);
            av1 = *(const uint4*)(A + (size_t)gm * K + kk + c2 + 8);
        } else { av0 = make_uint4(0,0,0,0); av1 = av0; }
        *(uint4*)&As[row * 72 + c2]     = av0;
        *(uint4*)&As[row * 72 + c2 + 8] = av1;
        uint4 bv0 = *(const uint4*)(Bt + (size_t)(n0 + row) * K + kk + c2);
        uint4 bv1 = *(const uint4*)(Bt + (size_t)(n0 + row) * K + kk + c2 + 8);
        *(uint4*)&Bs[row * 72 + c2]     = bv0;
        *(uint4*)&Bs[row * 72 + c2 + 8] = bv1;
        __syncthreads();
#pragma unroll
        for (int ks = 0; ks < 2; ++ks) {
            short8 a = *(const short8*)&As[(wave * 16 + (lane & 15)) * 72 + ks * 32 + (lane >> 4) * 8];
#pragma unroll
            for (int g = 0; g < 4; ++g) {
                short8 b = *(const short8*)&Bs[(g * 16 + (lane & 15)) * 72 + ks * 32 + (lane >> 4) * 8];
                acc[g] = __builtin_amdgcn_mfma_f32_16x16x32_bf16(a, b, acc[g], 0, 0, 0);
            }
        }
        __syncthreads();
    }
#pragma unroll
    for (int g = 0; g < 4; ++g) {
        int col = n0 + g * 16 + (lane & 15);
        float bs = bias[col];
#pragma unroll
        for (int r = 0; r < 4; ++r) {
            int grow = m0 + wave * 16 + (lane >> 4) * 4 + r;
            if (grow < M) {
                unsigned char c = f2fp8(acc[g][r] + bs);
                if (col < split) Cv[(size_t)grow * split + col] = c;
                else             Cv2[(size_t)grow * split + (col - split)] = c;
            }
        }
    }
}

// ---------------------------------------------------------------------------
// HYBRID: edge_scatter + layer-1 GEMM in ONE launch (independent work;
// R13 win: −16us).  Block-parity interleave co-schedules the atomic/
// latency-bound scatter with the MFMA-bound GEMM on every CU.
// ---------------------------------------------------------------------------
__global__ void __launch_bounds__(256)
scat_gemm1(const int* __restrict__ ei, const float* __restrict__ ea,
           int* __restrict__ wptr_pad, int2* __restrict__ spk, int E, int NS,
           const unsigned short* __restrict__ A, const unsigned short* __restrict__ Bt,
           const float* __restrict__ bias, unsigned char* __restrict__ Cv,
           unsigned char* __restrict__ Cv2, int split, int M, int N, int K, int GB) {
    __shared__ __attribute__((aligned(16))) unsigned short As[64 * 72];
    __shared__ __attribute__((aligned(16))) unsigned short Bs[64 * 72];
    int bid = blockIdx.x;
    int nmin = imin(NS, GB);
    bool is_scat;
    int idx;
    if (bid < 2 * nmin) { is_scat = !(bid & 1); idx = bid >> 1; }
    else                { idx = bid - nmin;     is_scat = (NS > GB); }

    if (is_scat) {
        int e = idx * 256 + threadIdx.x;
        if (e < E) {
            int d = ei[E + e];
            int pos = atomicAdd(&wptr_pad[(size_t)d * 16], 1);
            spk[pos] = make_int2(ei[e], __float_as_int(ea[e]));
        }
        return;
    }
    int GY = N >> 6;
    int bx = idx / GY, by = idx - bx * GY;
    gemm_body(A, Bt, bias, Cv, Cv2, split, M, N, K, bx, by, As, Bs);
}

// ---------------------------------------------------------------------------
// layer-2 GEMM (fp8 split output), BK=64 body.
// ---------------------------------------------------------------------------
__global__ void __launch_bounds__(256)
gemm_fp8(const unsigned short* __restrict__ A, const unsigned short* __restrict__ Bt,
         const float* __restrict__ bias, unsigned char* __restrict__ Cv,
         unsigned char* __restrict__ Cv2, int split, int M, int N, int K) {
    __shared__ __attribute__((aligned(16))) unsigned short As[64 * 72];
    __shared__ __attribute__((aligned(16))) unsigned short Bs[64 * 72];
    gemm_body(A, Bt, bias, Cv, Cv2, split, M, N, K, blockIdx.x, blockIdx.y, As, Bs);
}

// ---------------------------------------------------------------------------
// helpers for gat_agg (fp8 gather, packed-f32 math)
// ---------------------------------------------------------------------------
template <int NV>
__device__ __forceinline__ void unp1(unsigned int u, v2f* xf) {
    xf[0] = __builtin_amdgcn_cvt_pk_f32_fp8(u, false);
    if constexpr (NV == 4) xf[1] = __builtin_amdgcn_cvt_pk_f32_fp8(u, true);
}
// reduction over G consecutive lanes (G-aligned groups), full 64-lane wave
template <int G>
__device__ __forceinline__ float grp_reduce(float vs) {
    vs = dpp_add<0xB1>(vs);                               // xor 1
    if constexpr (G >= 4)  vs = dpp_add<0x4E>(vs);        // xor 2
    if constexpr (G >= 8)  vs = dpp_add<0x141>(vs);       // xor 4 (row_half_mirror)
    if constexpr (G >= 16) vs = dpp_add<0x140>(vs);       // xor 8 (row_mirror)
    if constexpr (G >= 32) {                              // xor 16
        int t = __builtin_amdgcn_ds_swizzle(__float_as_int(vs), 0x401F);
        vs += __int_as_float(t);
    }
    if constexpr (G >= 64) vs += __shfl_xor(vs, 32, 64);  // xor 32
    return vs;
}

// ---------------------------------------------------------------------------
// fused GATv2 gather(fp8) + score + softmax + aggregate + relu.
// ONE EDGE PER FULL WAVE, depth-6 mov-free register gather pipeline, dense
// xl/xr split tables (best measured config; the gather-softmax phase is at
// its structural plateau per the R2-R11 ledger).
// OUT_MODE 0: dense bf16 rows.
// OUT_MODE 1: LDS block-reduction (4 waves) then 128 atomics per BLOCK.
// ---------------------------------------------------------------------------
template <int HC, int C, int OUT_MODE>
__global__ void __launch_bounds__(256)
gat_agg(const unsigned char* __restrict__ xl, const unsigned char* __restrict__ xr,
        const float* __restrict__ We, const float* __restrict__ att,
        const float* __restrict__ bias,
        const int* __restrict__ row_ptr, const int2* __restrict__ spk,
        const float* __restrict__ ea_loop,
        void* __restrict__ out, int n) {
    constexpr int NV = HC / 64;      // channels (bytes) per lane, full-wave row
    constexpr int NG = (NV + 1) / 2; // v2f groups per lane (NV=4 -> 2, NV=2 -> 1)
    constexpr int G  = C / NV;       // lanes per head
    constexpr int SHIFT = (HC == 256) ? 8 : 7;   // dense xl row stride
    constexpr float K23 = 2.0f / 3.0f;
    __shared__ float red[4][128];    // OUT_MODE 1 block pooling reduction
    int wave = threadIdx.x >> 6;
    int lane = threadIdx.x & 63;
    int node = blockIdx.x * 4 + wave;
    bool active = node < n;
    if (OUT_MODE == 0 && !active) return;
    unsigned int lo = (unsigned int)lane * NV;   // channel/byte offset

    float vout[NV];
#pragma unroll
    for (int j = 0; j < NV; ++j) vout[j] = 0.0f;

    if (active) {
        auto ldd = [&](const unsigned char* base, unsigned int off) -> unsigned int {
            if constexpr (NV == 4) return *(const unsigned int*)(base + off);
            else                   return (unsigned int)(*(const unsigned short*)(base + off));
        };
        auto gat = [&](int s) -> unsigned int {
            return ldd(xl, ((unsigned int)s << SHIFT) + lo);
        };
        auto W = [&](int2 s) -> float { return __int_as_float(s.y); };

        v2f xr2[NG], We2[NG], att62[NG], o2[NG];
        {
            v2f tmp[NG];
            unp1<NV>(ldd(xr, ((unsigned int)node << SHIFT) + lo), tmp);
#pragma unroll
            for (int g = 0; g < NG; ++g) xr2[g] = tmp[g];
        }
#pragma unroll
        for (int g = 0; g < NG; ++g) {
            We2[g]   = *(const v2f*)(We  + lo + 2 * g);
            v2f a    = *(const v2f*)(att + lo + 2 * g);
            att62[g] = a * (0.6f * LOG2E);
            o2[g]    = v2f{0.0f, 0.0f};
        }
        float l = 0.0f;

        int start = __builtin_amdgcn_readfirstlane(row_ptr[node]);
        int end   = __builtin_amdgcn_readfirstlane(row_ptr[node + 1]);
        float ea_l = ea_loop[node];

        auto process = [&](unsigned int du, float w) {
            v2f xf[NG];
            unp1<NV>(du, xf);
            v2f w2 = {w, w};
            v2f vs6 = {0.0f, 0.0f};
            float vs4 = 0.0f;
#pragma unroll
            for (int g = 0; g < NG; ++g) {
                v2f t  = pk_fma(w2, We2[g], xr2[g]);     // xr + w*We
                v2f mm = pk_add(xf[g], t);               // xl[src] + xr + w*We
                vs6 = pk_fma(att62[g], mm, vs6);
                vs4 = fmaf(fabsf(mm.x), att62[g].x, vs4);   // abs = free modifier
                vs4 = fmaf(fabsf(mm.y), att62[g].y, vs4);
            }
            float vs = fmaf(K23, vs4, vs6.x + vs6.y);
            vs = grp_reduce<G>(vs);
            float pr = fast_exp2(vs);
            l += pr;
            v2f pr2 = {pr, pr};
#pragma unroll
            for (int g = 0; g < NG; ++g) o2[g] = pk_fma(xf[g], pr2, o2[g]);
        };

        // ---- self-loop edge ----
        process(gat(node), ea_l);

        // ---- real edges: 6-deep mov-free gather pipeline ----
        int cnt = end - start;
        const int2* q = spk + start;   // wave-uniform meta per edge

        if (cnt >= 6) {
            int2 t;
            t = q[0]; unsigned int g0 = gat(t.x); float w0 = W(t);
            t = q[1]; unsigned int g1 = gat(t.x); float w1 = W(t);
            t = q[2]; unsigned int g2 = gat(t.x); float w2 = W(t);
            t = q[3]; unsigned int g3 = gat(t.x); float w3 = W(t);
            t = q[4]; unsigned int g4 = gat(t.x); float w4 = W(t);
            t = q[5]; unsigned int g5 = gat(t.x); float w5 = W(t);
            int p = 0;
            // invariant at loop top: g0..g5 / w0..w5 hold edges p..p+5
            for (; p + 12 <= cnt; p += 6) {
                process(g0, w0); t = q[p + 6];  g0 = gat(t.x); w0 = W(t);
                process(g1, w1); t = q[p + 7];  g1 = gat(t.x); w1 = W(t);
                process(g2, w2); t = q[p + 8];  g2 = gat(t.x); w2 = W(t);
                process(g3, w3); t = q[p + 9];  g3 = gat(t.x); w3 = W(t);
                process(g4, w4); t = q[p + 10]; g4 = gat(t.x); w4 = W(t);
                process(g5, w5); t = q[p + 11]; g5 = gat(t.x); w5 = W(t);
            }
            // r = cnt - p in [6, 11]
            process(g0, w0); process(g1, w1); process(g2, w2);
            process(g3, w3); process(g4, w4); process(g5, w5);
            for (int k = p + 6; k < cnt; ++k) {
                t = q[k];
                process(gat(t.x), W(t));
            }
        } else {
            for (int k = 0; k < cnt; ++k) {
                int2 t = q[k];
                process(gat(t.x), W(t));
            }
        }

        // ---- epilogue: every lane owns its NV channels and full head denom ----
        float inv = 1.0f / (l + 1e-16f);
#pragma unroll
        for (int g = 0; g < NG; ++g) {
            v2f b = *(const v2f*)(bias + lo + 2 * g);
            vout[2 * g]     = fmaxf(o2[g].x * inv + b.x, 0.0f);
            vout[2 * g + 1] = fmaxf(o2[g].y * inv + b.y, 0.0f);
        }
        if constexpr (OUT_MODE == 0) {
            unsigned short* op = (unsigned short*)out + (size_t)node * HC + lo;
            if constexpr (NV == 4) {
                uint2 t;
                t.x = f2bf(vout[0]) | (f2bf(vout[1]) << 16);
                t.y = f2bf(vout[2]) | (f2bf(vout[3]) << 16);
                *(uint2*)op = t;
            } else {
                *(unsigned int*)op = f2bf(vout[0]) | (f2bf(vout[1]) << 16);
            }
        }
    }

    if constexpr (OUT_MODE == 1) {
        // block-level pooling reduction: 4 waves -> LDS -> one atomic pass
#pragma unroll
        for (int j = 0; j < NV; ++j) red[wave][lo + j] = vout[j];
        __syncthreads();
        if (wave == 0) {
            int c = lane;   // channels c and c+64
            float a = red[0][c] + red[1][c] + red[2][c] + red[3][c];
            float b = red[0][c + 64] + red[1][c + 64] + red[2][c + 64] + red[3][c + 64];
            float* pacc = (float*)out + (size_t)(blockIdx.x & 255) * 128;
            atomicAdd(&pacc[c], a);
            atomicAdd(&pacc[c + 64], b);
        }
    }
}

// ---------------------------------------------------------------------------
// finish pooling, softmax over 128, sigmoid(alpha). 1024 threads.
// ---------------------------------------------------------------------------
__global__ void __launch_bounds__(1024)
pool_final(const float* __restrict__ partial, int nb,
           const float* __restrict__ alpha_in,
           float* __restrict__ out, int n) {
    __shared__ float acc[8][128];
    __shared__ float red[4];
    int t = threadIdx.x & 127;        // column
    int g = threadIdx.x >> 7;         // group 0..7
    float s = 0.0f;
    for (int b = g; b < nb; b += 8) s += partial[b * 128 + t];
    acc[g][t] = s;
    __syncthreads();
    if (threadIdx.x < 128) {
        float tot = 0.0f;
#pragma unroll
        for (int k = 0; k < 8; ++k) tot += acc[k][t];
        float mean = tot / (float)n;
        float mx = mean;
#pragma unroll
        for (int off = 32; off > 0; off >>= 1) mx = fmaxf(mx, __shfl_xor(mx, off, 64));
        if ((t & 63) == 0) red[t >> 6] = mx;
        __syncthreads();
        mx = fmaxf(red[0], red[1]);
        float ex = __expf(mean - mx);
        float sm = ex;
#pragma unroll
        for (int off = 32; off > 0; off >>= 1) sm += __shfl_xor(sm, off, 64);
        if ((t & 63) == 0) red[2 + (t >> 6)] = sm;
        __syncthreads();
        sm = red[2] + red[3];
        out[t] = ex / sm;
        if (t == 0) out[128] = 1.0f / (1.0f + __expf(-alpha_in[0]));
    }
}

// ---------------------------------------------------------------------------
extern "C" void kernel_launch(void* const* d_in, const int* in_sizes, int n_in,
                              void* d_out, int out_size, void* d_ws, size_t ws_size,
                              hipStream_t stream) {
    const float* x    = (const float*)d_in[0];
    const int*   ei   = (const int*)d_in[1];
    const float* ea   = (const float*)d_in[2];
    const float* W1l  = (const float*)d_in[3];
    const float* b1l  = (const float*)d_in[4];
    const float* W1r  = (const float*)d_in[5];
    const float* b1r  = (const float*)d_in[6];
    const float* We1  = (const float*)d_in[7];
    const float* att1 = (const float*)d_in[8];
    const float* bias1= (const float*)d_in[9];
    const float* W2l  = (const float*)d_in[10];
    const float* b2l  = (const float*)d_in[11];
    const float* W2r  = (const float*)d_in[12];
    const float* b2r  = (const float*)d_in[13];
    const float* We2  = (const float*)d_in[14];
    const float* att2 = (const float*)d_in[15];
    const float* bias2= (const float*)d_in[16];
    const float* alpha= (const float*)d_in[17];
    float* out = (float*)d_out;

    const int F = 128, HC1 = 256, HC2 = 128;
    const int n = in_sizes[0] / F;       // 20000
    const int E = in_sizes[1] / 2;       // 640000
    const int B = (n + 1023) / 1024;     // scan blocks

    char* ws = (char*)d_ws;
    size_t off = 0;
    auto alloc = [&](size_t bytes) { size_t p = off; off += (bytes + 255) & ~(size_t)255; return p; };

    unsigned long long* hist = (unsigned long long*)(ws + alloc((size_t)n * 8 * 8 + 256));  // +ctr
    int*   sctr    = (int*)((char*)hist + (size_t)n * 64);
    int*   row_ptr = (int*)  (ws + alloc((size_t)(n + 1) * 4));
    int*   wptr    = (int*)  (ws + alloc((size_t)n * 16 * 4));                        // padded x16
    float* ea_loop = (float*)(ws + alloc((size_t)n * 4));
    int*   bsum    = (int*)  (ws + alloc(64 * 4));
    int2*  spk     = (int2*) (ws + alloc((size_t)E * 8));
    unsigned short* xb   = (unsigned short*)(ws + alloc((size_t)n * F * 2));
    unsigned short* Wt1  = (unsigned short*)(ws + alloc((size_t)F * (2 * HC1) * 2));
    unsigned short* Wt2  = (unsigned short*)(ws + alloc((size_t)HC1 * (2 * HC2) * 2));
    float* b1cat   = (float*)(ws + alloc((size_t)2 * HC1 * 4));
    float* b2cat   = (float*)(ws + alloc((size_t)2 * HC2 * 4));
    unsigned char* xl1 = (unsigned char*)(ws + alloc((size_t)n * HC1));   // dense fp8 xl table
    unsigned char* xr1 = (unsigned char*)(ws + alloc((size_t)n * HC1));   // dense fp8 xr table
    unsigned short* h1  = (unsigned short*)(ws + alloc((size_t)n * HC1 * 2));  // bf16
    float* partial = (float*)(ws + alloc((size_t)256 * 128 * 4));
    unsigned char* xl2 = xl1;   // layer-2 tables alias layer-1 (dead by then)
    unsigned char* xr2 = xr1;
    const int NB_SLOTS = 256;

    (void)hipMemsetAsync(hist, 0, (size_t)n * 8 * 8 + 256, stream);   // hist + sctr
    (void)hipMemsetAsync(partial, 0, (size_t)NB_SLOTS * 128 * 4, stream);

    int tb = 256;
    {
        int nF4  = n * F / 4;
        int WTOT = 2 * F * HC1 + 2 * HC1 * HC2 + 2 * HC1 + 2 * HC2;
        int total = E + nF4 + WTOT;
        fused_prep<<<(total + tb - 1) / tb, tb, 0, stream>>>(
            ei, ea, hist, E, x, xb, nF4,
            W1l, W1r, W2l, W2r, b1l, b1r, b2l, b2r,
            Wt1, Wt2, b1cat, b2cat, F, HC1, HC2);
    }
    // merged scan (scan_a + scan_c in one launch, 20-block grid barrier)
    scan_fused<<<B, 256, 0, stream>>>(hist, bsum, sctr, row_ptr, wptr, ea_loop, n, B);

    // HYBRID: edge_scatter + layer-1 GEMM co-scheduled in one launch
    {
        int NS = (E + 255) / 256;                         // 2500 scatter blocks
        int GB = ((n + 63) / 64) * ((2 * HC1) / 64);      // 2504 gemm blocks
        int nmin = NS < GB ? NS : GB;
        int grid = 2 * nmin + (NS > GB ? NS - GB : GB - NS);
        scat_gemm1<<<grid, 256, 0, stream>>>(
            ei, ea, wptr, spk, E, NS,
            xb, Wt1, b1cat, xl1, xr1, HC1, n, 2 * HC1, F, GB);
    }
    gat_agg<256, 32, 0><<<(n + 3) / 4, 256, 0, stream>>>(
        xl1, xr1, We1, att1, bias1, row_ptr, spk, ea_loop, h1, n);

    // layer 2: merged GEMM [n,256]@[256,256] -> dense xl2 | xr2 (fp8)
    {
        dim3 grid((n + 63) / 64, (2 * HC2) / 64);
        gemm_fp8<<<grid, 256, 0, stream>>>(h1, Wt2, b2cat, xl2, xr2, HC2, n, 2 * HC2, HC1);
    }
    // layer-2 gat with fused pooling (LDS block-reduce + per-block atomics)
    gat_agg<128, 128, 1><<<(n + 3) / 4, 256, 0, stream>>>(
        xl2, xr2, We2, att2, bias2, row_ptr, spk, ea_loop, partial, n);

    pool_final<<<1, 1024, 0, stream>>>(partial, NB_SLOTS, alpha, out, n);
}